// Round 2
// baseline (548.280 us; speedup 1.0000x reference)
//
#include <hip/hip_runtime.h>
#include <hip/hip_bf16.h>

#define INFV 1e9f
#define EPSV 1e-5f

typedef unsigned short u16;
typedef unsigned int u32;
typedef __attribute__((ext_vector_type(8))) short short8;   // 8 bf16 (MFMA A/B frag)
typedef __attribute__((ext_vector_type(4))) float float4v;  // MFMA C/D frag

__device__ __forceinline__ u16 f2us(float f) {
    u32 v;
    __builtin_memcpy(&v, &f, 4);
    u32 r = v + 0x7fffu + ((v >> 16) & 1u);
    return (u16)(r >> 16);
}

__device__ __forceinline__ float wred_sum(float x) {
    #pragma unroll
    for (int o = 32; o; o >>= 1) x += __shfl_xor(x, o);
    return x;
}
__device__ __forceinline__ float wred_max(float x) {
    #pragma unroll
    for (int o = 32; o; o >>= 1) x = fmaxf(x, __shfl_xor(x, o));
    return x;
}

// ---------------- LN(m) -> mn bf16, + weight prep (merged grid) ----------------
__global__ __launch_bounds__(256) void k_prep_ln(
    const float* __restrict__ m, const float* __restrict__ gm, const float* __restrict__ bm,
    u16* __restrict__ mn,
    const float* __restrict__ wv, const float* __restrict__ wg,
    const float* __restrict__ wo, const float* __restrict__ wz,
    u16* __restrict__ wv_t, u16* __restrict__ wg_t,
    u16* __restrict__ wo_t, u16* __restrict__ wzT)
{
    if (blockIdx.x < 12288) {
        const int tid  = threadIdx.x;
        const int wid  = tid >> 6;
        const int lane = tid & 63;
        const int rloc = lane >> 4;
        const int c4   = (lane & 15) * 4;
        const int row  = blockIdx.x * 16 + wid * 4 + rloc;   // 0..196607
        const float4 x = *(const float4*)(m + (size_t)row * 64 + c4);
        float s1 = x.x + x.y + x.z + x.w;
        float s2 = x.x * x.x + x.y * x.y + x.z * x.z + x.w * x.w;
        #pragma unroll
        for (int o = 8; o; o >>= 1) { s1 += __shfl_xor(s1, o); s2 += __shfl_xor(s2, o); }
        const float mean = s1 * (1.0f / 64.0f);
        const float var  = s2 * (1.0f / 64.0f) - mean * mean;
        const float rs   = rsqrtf(var + EPSV);
        const float4 g = *(const float4*)(gm + c4);
        const float4 b = *(const float4*)(bm + c4);
        uint2 pk;
        pk.x = (u32)f2us((x.x - mean) * rs * g.x + b.x) | ((u32)f2us((x.y - mean) * rs * g.y + b.y) << 16);
        pk.y = (u32)f2us((x.z - mean) * rs * g.z + b.z) | ((u32)f2us((x.w - mean) * rs * g.w + b.w) << 16);
        *(uint2*)(mn + (size_t)row * 64 + c4) = pk;
    } else {
        const int i = (blockIdx.x - 12288) * 256 + threadIdx.x;   // 0..51199
        if (i < 16384) {
            const int n = i >> 6, k = i & 63;
            wv_t[i] = f2us(wv[(size_t)k * 256 + n]);
        } else if (i < 32768) {
            const int j = i - 16384, n = j >> 6, k = j & 63;
            wg_t[j] = f2us(wg[(size_t)k * 256 + n]);
        } else if (i < 49152) {
            const int j = i - 32768, n = j >> 8, k = j & 255;
            wo_t[j] = f2us(wo[(size_t)k * 64 + n]);
        } else if (i < 51200) {
            const int j = i - 49152, n = j >> 7, k = j & 127;
            wzT[j] = (n < 8) ? f2us(wz[(size_t)k * 8 + n]) : (u16)0;
        }
    }
}

// ---------------- vT producer: vT[s][hc][k] = (mn @ wv)^T, bf16 ----------------
// grid (6 ktiles, 512 s), 4 waves/block; wave owns 16 k-rows x 256 hc.
// Removes the per-chunk v-GEMM + LDS + barrier from the fused kernel entirely.
__global__ __launch_bounds__(256) void k_vT(
    const u16* __restrict__ mn, const u16* __restrict__ wv_t, u16* __restrict__ vT)
{
    const int tid  = threadIdx.x;
    const int wid  = tid >> 6;
    const int lane = tid & 63;
    const int lrow = lane & 15;
    const int lkg  = lane >> 4;
    const int s    = blockIdx.y;
    const int k0   = blockIdx.x * 64 + wid * 16;   // this wave's 16 k-rows

    const u16* mnk = mn + ((size_t)s * 384 + k0 + lrow) * 64;
    const short8 a0 = *(const short8*)(mnk + lkg * 8);
    const short8 a1 = *(const short8*)(mnk + 32 + lkg * 8);

    #pragma unroll
    for (int nt = 0; nt < 16; nt++) {
        const short8 b0 = *(const short8*)(wv_t + (size_t)(nt * 16 + lrow) * 64 + lkg * 8);
        const short8 b1 = *(const short8*)(wv_t + (size_t)(nt * 16 + lrow) * 64 + 32 + lkg * 8);
        float4v acc = (float4v){0.f, 0.f, 0.f, 0.f};
        acc = __builtin_amdgcn_mfma_f32_16x16x32_bf16(a0, b0, acc, 0, 0, 0);
        acc = __builtin_amdgcn_mfma_f32_16x16x32_bf16(a1, b1, acc, 0, 0, 0);
        // lane holds hc = nt*16+lrow, k = k0 + lkg*4 + r  -> 4 contiguous k in vT
        uint2 pk;
        pk.x = (u32)f2us(acc[0]) | ((u32)f2us(acc[1]) << 16);
        pk.y = (u32)f2us(acc[2]) | ((u32)f2us(acc[3]) << 16);
        *(uint2*)(vT + (size_t)(s * 256 + nt * 16 + lrow) * 384 + k0 + lkg * 4) = pk;
    }
}

// ---------------- logits via MFMA ----------------
__global__ __launch_bounds__(256) void k_logits2(
    const float* __restrict__ z, const float* __restrict__ mask,
    const float* __restrict__ gz, const float* __restrict__ bz,
    const u16* __restrict__ wzT, const float* __restrict__ bzb,
    float* __restrict__ wbuf)
{
    const int tid   = threadIdx.x;
    const int wid   = tid >> 6;
    const int lane  = tid & 63;
    const int lrow  = lane & 15;
    const int lkg   = lane >> 4;
    const int pair0 = (blockIdx.x * 4 + wid) * 16;

    float x[4][8];
    float s1 = 0.0f, s2 = 0.0f;
    #pragma unroll
    for (int ks = 0; ks < 4; ks++) {
        const float4* zp = (const float4*)(z + (size_t)(pair0 + lrow) * 128 + ks * 32 + lkg * 8);
        const float4 a = zp[0], b = zp[1];
        x[ks][0] = a.x; x[ks][1] = a.y; x[ks][2] = a.z; x[ks][3] = a.w;
        x[ks][4] = b.x; x[ks][5] = b.y; x[ks][6] = b.z; x[ks][7] = b.w;
        #pragma unroll
        for (int j = 0; j < 8; j++) { s1 += x[ks][j]; s2 += x[ks][j] * x[ks][j]; }
    }
    s1 += __shfl_xor(s1, 16); s1 += __shfl_xor(s1, 32);
    s2 += __shfl_xor(s2, 16); s2 += __shfl_xor(s2, 32);
    const float mean = s1 * (1.0f / 128.0f);
    const float var  = s2 * (1.0f / 128.0f) - mean * mean;
    const float rs   = rsqrtf(var + EPSV);

    float4v acc = (float4v){0.f, 0.f, 0.f, 0.f};
    #pragma unroll
    for (int ks = 0; ks < 4; ks++) {
        const int c0 = ks * 32 + lkg * 8;
        const float4 g0 = *(const float4*)(gz + c0);
        const float4 g1 = *(const float4*)(gz + c0 + 4);
        const float4 b0 = *(const float4*)(bz + c0);
        const float4 b1 = *(const float4*)(bz + c0 + 4);
        const float gv[8] = {g0.x, g0.y, g0.z, g0.w, g1.x, g1.y, g1.z, g1.w};
        const float bvv[8] = {b0.x, b0.y, b0.z, b0.w, b1.x, b1.y, b1.z, b1.w};
        short8 afr;
        #pragma unroll
        for (int j = 0; j < 8; j++)
            afr[j] = (short)f2us((x[ks][j] - mean) * rs * gv[j] + bvv[j]);
        const short8 bfr = *(const short8*)(wzT + (size_t)lrow * 128 + c0);
        acc = __builtin_amdgcn_mfma_f32_16x16x32_bf16(afr, bfr, acc, 0, 0, 0);
    }
    if (lrow < 8) {
        const float bzv = bzb[lrow];
        #pragma unroll
        for (int r = 0; r < 4; r++) {
            const int p = pair0 + lkg * 4 + r;
            const float mb = INFV * (mask[p] - 1.0f);
            wbuf[(size_t)lrow * 147456 + p] = acc[r] + bzv + mb;
        }
    }
}

// ---------------- softmax over k per (h,q) row; fp32 -> bf16 ----------------
__global__ __launch_bounds__(256) void k_softmax(
    const float* __restrict__ wbuf, u16* __restrict__ wb16)
{
    const int r = blockIdx.x * 4 + (threadIdx.x >> 6);
    const int lane = threadIdx.x & 63;
    const float* base = wbuf + (size_t)r * 384;
    float v[6];
    float mx = -1e30f;
    #pragma unroll
    for (int j = 0; j < 6; j++) {
        v[j] = base[lane + j * 64];
        mx = fmaxf(mx, v[j]);
    }
    mx = wred_max(mx);
    float s = 0.0f;
    #pragma unroll
    for (int j = 0; j < 6; j++) {
        v[j] = __expf(v[j] - mx);
        s += v[j];
    }
    s = wred_sum(s);
    const float inv = 1.0f / s;
    u16* ob = wb16 + (size_t)r * 384;
    #pragma unroll
    for (int j = 0; j < 6; j++) ob[lane + j * 64] = f2us(v[j] * inv);
}

// ---------------- fused6: barrier-free o-GEMM (vT from global) + epilogue ----------------
// 1D grid 1536 = 8 XCD x 192; bijective swizzle puts all 3 q-tiles of an s on one XCD
// (vT[s] slice = 196 KB and wb16 = 2.3 MB stay L2-resident per XCD).
// Main loop: NO LDS, NO barrier, NO packing -> waves fully independent, latency self-hiding.
__global__ __launch_bounds__(256, 2) void k_fused6(
    const u16* __restrict__ mn, const u16* __restrict__ vT,
    const float* __restrict__ bv, const float* __restrict__ bg, const float* __restrict__ bo,
    const u16* __restrict__ wg_t, const u16* __restrict__ wo_t,
    const u16* __restrict__ wb16, float* __restrict__ out)
{
    __shared__ __align__(16) u16 og[128 * 264];   // epilogue o*g tile only

    const int tid  = threadIdx.x;
    const int wid  = tid >> 6;
    const int lane = tid & 63;
    const int lrow = lane & 15;
    const int lkg  = lane >> 4;

    // XCD-aware bijective swizzle: 1536 blocks = 8 * 192
    const int bid  = blockIdx.x;
    const int xcd  = bid & 7;
    const int slot = bid >> 3;          // 0..191
    const int sdiv = slot / 3;          // 0..63
    const int q0   = (slot - sdiv * 3) * 128;
    const int s    = sdiv * 8 + xcd;    // 0..511

    // oacc[mt*16+nt]: q-rows q0+wid*32+mt*16.., hc tile nt. Init = bv (softmax sums to 1).
    float4v oacc[32];
    #pragma unroll
    for (int mt = 0; mt < 2; mt++)
        #pragma unroll
        for (int nt = 0; nt < 16; nt++) {
            const float b = bv[nt * 16 + lrow];
            oacc[mt * 16 + nt] = (float4v){b, b, b, b};
        }

    const u16* vTs = vT + (size_t)s * 98304;                 // [256][384]
    const u16* wbq = wb16 + (size_t)(q0 + wid * 32 + lrow) * 384;

    for (int kt = 0; kt < 12; kt++) {
        const int k0 = kt * 32;
        short8 ah[2][8];
        #pragma unroll
        for (int mt = 0; mt < 2; mt++)
            #pragma unroll
            for (int h = 0; h < 8; h++)
                ah[mt][h] = *(const short8*)(wbq + (size_t)h * 147456 + (size_t)mt * 16 * 384 + k0 + lkg * 8);
        #pragma unroll
        for (int nt = 0; nt < 16; nt++) {
            const short8 b = *(const short8*)(vTs + (size_t)(nt * 16 + lrow) * 384 + k0 + lkg * 8);
            oacc[nt]      = __builtin_amdgcn_mfma_f32_16x16x32_bf16(ah[0][nt >> 1], b, oacc[nt], 0, 0, 0);
            oacc[16 + nt] = __builtin_amdgcn_mfma_f32_16x16x32_bf16(ah[1][nt >> 1], b, oacc[16 + nt], 0, 0, 0);
        }
    }

    // ---- g-GEMM + sigmoid + o*g -> og; weight frags shared across both mt ----
    {
        const u16* mnq = mn + ((size_t)s * 384 + q0 + wid * 32 + lrow) * 64;
        const short8 a00 = *(const short8*)(mnq + lkg * 8);
        const short8 a01 = *(const short8*)(mnq + 32 + lkg * 8);
        const short8 a10 = *(const short8*)(mnq + 16 * 64 + lkg * 8);
        const short8 a11 = *(const short8*)(mnq + 16 * 64 + 32 + lkg * 8);
        #pragma unroll
        for (int nt = 0; nt < 16; nt++) {
            const float bgv = bg[nt * 16 + lrow];
            const short8 b0 = *(const short8*)(wg_t + (size_t)(nt * 16 + lrow) * 64 + lkg * 8);
            const short8 b1 = *(const short8*)(wg_t + (size_t)(nt * 16 + lrow) * 64 + 32 + lkg * 8);
            float4v g0 = (float4v){bgv, bgv, bgv, bgv};
            float4v g1 = (float4v){bgv, bgv, bgv, bgv};
            g0 = __builtin_amdgcn_mfma_f32_16x16x32_bf16(a00, b0, g0, 0, 0, 0);
            g0 = __builtin_amdgcn_mfma_f32_16x16x32_bf16(a01, b1, g0, 0, 0, 0);
            g1 = __builtin_amdgcn_mfma_f32_16x16x32_bf16(a10, b0, g1, 0, 0, 0);
            g1 = __builtin_amdgcn_mfma_f32_16x16x32_bf16(a11, b1, g1, 0, 0, 0);
            #pragma unroll
            for (int r = 0; r < 4; r++) {
                const float s0 = 1.0f / (1.0f + __expf(-g0[r]));
                const float s1 = 1.0f / (1.0f + __expf(-g1[r]));
                og[(size_t)(wid * 32 + lkg * 4 + r) * 264 + nt * 16 + lrow]      = f2us(oacc[nt][r] * s0);
                og[(size_t)(wid * 32 + 16 + lkg * 4 + r) * 264 + nt * 16 + lrow] = f2us(oacc[16 + nt][r] * s1);
            }
        }
    }
    __syncthreads();

    // ---- out-GEMM: A from og (LDS), B from wo_t shared across both mt ----
    {
        short8 af0[8], af1[8];
        #pragma unroll
        for (int ks = 0; ks < 8; ks++) {
            af0[ks] = *(const short8*)&og[(size_t)(wid * 32 + lrow) * 264 + ks * 32 + lkg * 8];
            af1[ks] = *(const short8*)&og[(size_t)(wid * 32 + 16 + lrow) * 264 + ks * 32 + lkg * 8];
        }
        #pragma unroll
        for (int nt = 0; nt < 4; nt++) {
            const float bov = bo[nt * 16 + lrow];
            float4v f0 = (float4v){bov, bov, bov, bov};
            float4v f1 = (float4v){bov, bov, bov, bov};
            #pragma unroll
            for (int ks = 0; ks < 8; ks++) {
                const short8 b = *(const short8*)(wo_t + (size_t)(nt * 16 + lrow) * 256 + ks * 32 + lkg * 8);
                f0 = __builtin_amdgcn_mfma_f32_16x16x32_bf16(af0[ks], b, f0, 0, 0, 0);
                f1 = __builtin_amdgcn_mfma_f32_16x16x32_bf16(af1[ks], b, f1, 0, 0, 0);
            }
            #pragma unroll
            for (int r = 0; r < 4; r++) {
                out[((size_t)s * 384 + q0 + wid * 32 + lkg * 4 + r) * 64 + nt * 16 + lrow]      = f0[r];
                out[((size_t)s * 384 + q0 + wid * 32 + 16 + lkg * 4 + r) * 64 + nt * 16 + lrow] = f1[r];
            }
        }
    }
}

// ---------------- fallback (round-0 kernel) if workspace can't fit vT ----------------
__global__ __launch_bounds__(256, 2) void k_fused4(
    const u16* __restrict__ mn,
    const float* __restrict__ bv, const float* __restrict__ bg, const float* __restrict__ bo,
    const u16* __restrict__ wv_t, const u16* __restrict__ wg_t, const u16* __restrict__ wo_t,
    const u16* __restrict__ wb16, float* __restrict__ out)
{
    __shared__ __align__(16) char smem[67584];
    u16* vtt = (u16*)smem;
    u16* og  = (u16*)smem;

    const int tid  = threadIdx.x;
    const int wid  = tid >> 6;
    const int lane = tid & 63;
    const int lrow = lane & 15;
    const int lkg  = lane >> 4;
    const int s    = blockIdx.y;
    const int q0   = blockIdx.x * 128;

    const int vmt  = wid & 1;
    const int vnt0 = (wid >> 1) * 8;

    float4v oacc[32];
    #pragma unroll
    for (int mt = 0; mt < 2; mt++)
        #pragma unroll
        for (int nt = 0; nt < 16; nt++) {
            const float b = bv[nt * 16 + lrow];
            oacc[mt * 16 + nt] = (float4v){b, b, b, b};
        }

    for (int kt = 0; kt < 12; kt++) {
        const int k0 = kt * 32;
        float4v vacc[8];
        #pragma unroll
        for (int nt = 0; nt < 8; nt++) vacc[nt] = (float4v){0.f, 0.f, 0.f, 0.f};
        const u16* mnk = mn + ((size_t)s * 384 + k0 + vmt * 16 + lrow) * 64;
        #pragma unroll
        for (int ks = 0; ks < 2; ks++) {
            const short8 a = *(const short8*)(mnk + ks * 32 + lkg * 8);
            #pragma unroll
            for (int nt = 0; nt < 8; nt++) {
                const short8 b = *(const short8*)(wv_t + (size_t)((vnt0 + nt) * 16 + lrow) * 64 + ks * 32 + lkg * 8);
                vacc[nt] = __builtin_amdgcn_mfma_f32_16x16x32_bf16(a, b, vacc[nt], 0, 0, 0);
            }
        }
        u16* vb = vtt + (size_t)(kt & 1) * 8192;
        const int kg8 = vmt * 2 + (lkg >> 1);
        const int ko  = (lkg & 1) * 4;
        #pragma unroll
        for (int nt = 0; nt < 8; nt++) {
            uint2 pk;
            pk.x = (u32)f2us(vacc[nt][0]) | ((u32)f2us(vacc[nt][1]) << 16);
            pk.y = (u32)f2us(vacc[nt][2]) | ((u32)f2us(vacc[nt][3]) << 16);
            *(uint2*)&vb[((size_t)kg8 * 256 + (vnt0 + nt) * 16 + lrow) * 8 + ko] = pk;
        }
        __syncthreads();

        short8 ah[2][8];
        #pragma unroll
        for (int mt = 0; mt < 2; mt++)
            #pragma unroll
            for (int h = 0; h < 8; h++)
                ah[mt][h] = *(const short8*)(wb16 + (size_t)h * 147456
                              + (size_t)(q0 + wid * 32 + mt * 16 + lrow) * 384 + k0 + lkg * 8);
        #pragma unroll
        for (int nt = 0; nt < 16; nt++) {
            const short8 b = *(const short8*)&vb[((size_t)lkg * 256 + nt * 16 + lrow) * 8];
            oacc[nt]      = __builtin_amdgcn_mfma_f32_16x16x32_bf16(ah[0][nt >> 1], b, oacc[nt], 0, 0, 0);
            oacc[16 + nt] = __builtin_amdgcn_mfma_f32_16x16x32_bf16(ah[1][nt >> 1], b, oacc[16 + nt], 0, 0, 0);
        }
    }
    __syncthreads();

    #pragma unroll
    for (int mt = 0; mt < 2; mt++) {
        const u16* mnq = mn + ((size_t)s * 384 + q0 + wid * 32 + mt * 16 + lrow) * 64;
        const short8 a0 = *(const short8*)(mnq + lkg * 8);
        const short8 a1 = *(const short8*)(mnq + 32 + lkg * 8);
        #pragma unroll
        for (int nt = 0; nt < 16; nt++) {
            const float bgv = bg[nt * 16 + lrow];
            float4v gacc = (float4v){bgv, bgv, bgv, bgv};
            const short8 b0 = *(const short8*)(wg_t + (size_t)(nt * 16 + lrow) * 64 + lkg * 8);
            const short8 b1 = *(const short8*)(wg_t + (size_t)(nt * 16 + lrow) * 64 + 32 + lkg * 8);
            gacc = __builtin_amdgcn_mfma_f32_16x16x32_bf16(a0, b0, gacc, 0, 0, 0);
            gacc = __builtin_amdgcn_mfma_f32_16x16x32_bf16(a1, b1, gacc, 0, 0, 0);
            #pragma unroll
            for (int r = 0; r < 4; r++) {
                const float sg = 1.0f / (1.0f + __expf(-gacc[r]));
                og[(size_t)(wid * 32 + mt * 16 + lkg * 4 + r) * 264 + nt * 16 + lrow]
                    = f2us(oacc[mt * 16 + nt][r] * sg);
            }
        }
    }
    __syncthreads();

    #pragma unroll
    for (int mt = 0; mt < 2; mt++) {
        short8 af[8];
        #pragma unroll
        for (int ks = 0; ks < 8; ks++)
            af[ks] = *(const short8*)&og[(size_t)(wid * 32 + mt * 16 + lrow) * 264 + ks * 32 + lkg * 8];
        #pragma unroll
        for (int nt = 0; nt < 4; nt++) {
            const float bov = bo[nt * 16 + lrow];
            float4v fac = (float4v){bov, bov, bov, bov};
            #pragma unroll
            for (int ks = 0; ks < 8; ks++) {
                const short8 b = *(const short8*)(wo_t + (size_t)(nt * 16 + lrow) * 256 + ks * 32 + lkg * 8);
                fac = __builtin_amdgcn_mfma_f32_16x16x32_bf16(af[ks], b, fac, 0, 0, 0);
            }
            #pragma unroll
            for (int r = 0; r < 4; r++)
                out[((size_t)s * 384 + q0 + wid * 32 + mt * 16 + lkg * 4 + r) * 64 + nt * 16 + lrow]
                    = fac[r];
        }
    }
}

extern "C" void kernel_launch(void* const* d_in, const int* in_sizes, int n_in,
                              void* d_out, int out_size, void* d_ws, size_t ws_size,
                              hipStream_t stream) {
    const float* m    = (const float*)d_in[0];
    const float* z    = (const float*)d_in[1];
    const float* mask = (const float*)d_in[2];
    const float* gm   = (const float*)d_in[3];
    const float* bm   = (const float*)d_in[4];
    const float* gz   = (const float*)d_in[5];
    const float* bz   = (const float*)d_in[6];
    const float* wz   = (const float*)d_in[7];
    const float* bzb  = (const float*)d_in[8];
    const float* wv   = (const float*)d_in[9];
    const float* bv   = (const float*)d_in[10];
    const float* wg   = (const float*)d_in[11];
    const float* bg   = (const float*)d_in[12];
    const float* wo   = (const float*)d_in[13];
    const float* bo   = (const float*)d_in[14];
    float* out = (float*)d_out;

    // ws layout
    char* ws = (char*)d_ws;
    float* wbuf = (float*)ws;                       // [8][147456] fp32 logits   4,718,592 B
    u16*  wb16  = (u16*)(ws + 4718592);             // [8][147456] bf16 weights  2,359,296 B
    u16*  mn    = (u16*)(ws + 7077888);             // [196608][64] bf16 LN(m)  25,165,824 B
    u16*  wv_t  = (u16*)(ws + 32243712);            // [256][64]  bf16
    u16*  wg_t  = (u16*)(ws + 32276480);            // [256][64]  bf16
    u16*  wo_t  = (u16*)(ws + 32309248);            // [64][256]  bf16
    u16*  wzT   = (u16*)(ws + 32342016);            // [16][128]  bf16
    u16*  vT    = (u16*)(ws + 32346112);            // [512][256][384] bf16 100,663,296 B

    const bool big = ws_size >= 133009408ull;

    k_prep_ln<<<12488, 256, 0, stream>>>(m, gm, bm, mn, wv, wg, wo, wz, wv_t, wg_t, wo_t, wzT);
    if (big)
        k_vT<<<dim3(6, 512), 256, 0, stream>>>(mn, wv_t, vT);
    k_logits2<<<2304, 256, 0, stream>>>(z, mask, gz, bz, wzT, bzb, wbuf);
    k_softmax<<<768,  256, 0, stream>>>(wbuf, wb16);
    if (big)
        k_fused6<<<1536, 256, 0, stream>>>(mn, vT, bv, bg, bo, wg_t, wo_t, wb16, out);
    else
        k_fused4<<<dim3(3, 512), 256, 0, stream>>>(mn, bv, bg, bo, wv_t, wg_t, wo_t, wb16, out);
}

// Round 3
// 422.449 us; speedup vs baseline: 1.2979x; 1.2979x over previous
//
#include <hip/hip_runtime.h>
#include <hip/hip_bf16.h>

#define INFV 1e9f
#define EPSV 1e-5f

typedef unsigned short u16;
typedef unsigned int u32;
typedef __attribute__((ext_vector_type(8))) short short8;   // 8 bf16 (MFMA A/B frag)
typedef __attribute__((ext_vector_type(4))) float float4v;  // MFMA C/D frag

__device__ __forceinline__ u16 f2us(float f) {
    u32 v;
    __builtin_memcpy(&v, &f, 4);
    u32 r = v + 0x7fffu + ((v >> 16) & 1u);
    return (u16)(r >> 16);
}

__device__ __forceinline__ float wred_sum(float x) {
    #pragma unroll
    for (int o = 32; o; o >>= 1) x += __shfl_xor(x, o);
    return x;
}
__device__ __forceinline__ float wred_max(float x) {
    #pragma unroll
    for (int o = 32; o; o >>= 1) x = fmaxf(x, __shfl_xor(x, o));
    return x;
}

// ---------------- LN(m) -> mn bf16, + weight prep (merged grid) ----------------
__global__ __launch_bounds__(256) void k_prep_ln(
    const float* __restrict__ m, const float* __restrict__ gm, const float* __restrict__ bm,
    u16* __restrict__ mn,
    const float* __restrict__ wv, const float* __restrict__ wg,
    const float* __restrict__ wo, const float* __restrict__ wz,
    u16* __restrict__ wv_t, u16* __restrict__ wg_t,
    u16* __restrict__ wo_t, u16* __restrict__ wzT)
{
    if (blockIdx.x < 12288) {
        const int tid  = threadIdx.x;
        const int wid  = tid >> 6;
        const int lane = tid & 63;
        const int rloc = lane >> 4;
        const int c4   = (lane & 15) * 4;
        const int row  = blockIdx.x * 16 + wid * 4 + rloc;   // 0..196607
        const float4 x = *(const float4*)(m + (size_t)row * 64 + c4);
        float s1 = x.x + x.y + x.z + x.w;
        float s2 = x.x * x.x + x.y * x.y + x.z * x.z + x.w * x.w;
        #pragma unroll
        for (int o = 8; o; o >>= 1) { s1 += __shfl_xor(s1, o); s2 += __shfl_xor(s2, o); }
        const float mean = s1 * (1.0f / 64.0f);
        const float var  = s2 * (1.0f / 64.0f) - mean * mean;
        const float rs   = rsqrtf(var + EPSV);
        const float4 g = *(const float4*)(gm + c4);
        const float4 b = *(const float4*)(bm + c4);
        uint2 pk;
        pk.x = (u32)f2us((x.x - mean) * rs * g.x + b.x) | ((u32)f2us((x.y - mean) * rs * g.y + b.y) << 16);
        pk.y = (u32)f2us((x.z - mean) * rs * g.z + b.z) | ((u32)f2us((x.w - mean) * rs * g.w + b.w) << 16);
        *(uint2*)(mn + (size_t)row * 64 + c4) = pk;
    } else {
        const int i = (blockIdx.x - 12288) * 256 + threadIdx.x;   // 0..51199
        if (i < 16384) {
            const int n = i >> 6, k = i & 63;
            wv_t[i] = f2us(wv[(size_t)k * 256 + n]);
        } else if (i < 32768) {
            const int j = i - 16384, n = j >> 6, k = j & 63;
            wg_t[j] = f2us(wg[(size_t)k * 256 + n]);
        } else if (i < 49152) {
            const int j = i - 32768, n = j >> 8, k = j & 255;
            wo_t[j] = f2us(wo[(size_t)k * 64 + n]);
        } else if (i < 51200) {
            const int j = i - 49152, n = j >> 7, k = j & 127;
            wzT[j] = (n < 8) ? f2us(wz[(size_t)k * 8 + n]) : (u16)0;
        }
    }
}

// ---------------- vT producer -> FRAGMENT-ORDERED vTf[s][kt][nt][lane][8] ----------------
// Consumer (k_fused7) reads one contiguous 1KB block per (kt,nt) B-frag: perfectly coalesced.
// Writer: wave writes 512B contiguous per nt (uint2/lane).
__global__ __launch_bounds__(256) void k_vT(
    const u16* __restrict__ mn, const u16* __restrict__ wv_t, u16* __restrict__ vTf)
{
    const int tid  = threadIdx.x;
    const int wid  = tid >> 6;
    const int lane = tid & 63;
    const int lrow = lane & 15;
    const int lkg  = lane >> 4;
    const int s    = blockIdx.y;
    const int k0   = blockIdx.x * 64 + wid * 16;   // this wave's 16 k-rows

    const int kt   = blockIdx.x * 2 + (wid >> 1);  // 32-k chunk index
    const int lkgc = (wid & 1) * 2 + (lkg >> 1);   // k-subgroup within chunk
    const int joff = (lkg & 1) * 4;

    const u16* mnk = mn + ((size_t)s * 384 + k0 + lrow) * 64;
    const short8 a0 = *(const short8*)(mnk + lkg * 8);
    const short8 a1 = *(const short8*)(mnk + 32 + lkg * 8);

    #pragma unroll
    for (int nt = 0; nt < 16; nt++) {
        const short8 b0 = *(const short8*)(wv_t + (size_t)(nt * 16 + lrow) * 64 + lkg * 8);
        const short8 b1 = *(const short8*)(wv_t + (size_t)(nt * 16 + lrow) * 64 + 32 + lkg * 8);
        float4v acc = (float4v){0.f, 0.f, 0.f, 0.f};
        acc = __builtin_amdgcn_mfma_f32_16x16x32_bf16(a0, b0, acc, 0, 0, 0);
        acc = __builtin_amdgcn_mfma_f32_16x16x32_bf16(a1, b1, acc, 0, 0, 0);
        // lane holds hc = nt*16+lrow, k = k0 + lkg*4 + r (4 contiguous k)
        uint2 pk;
        pk.x = (u32)f2us(acc[0]) | ((u32)f2us(acc[1]) << 16);
        pk.y = (u32)f2us(acc[2]) | ((u32)f2us(acc[3]) << 16);
        *(uint2*)(vTf + ((((size_t)s * 12 + kt) * 16 + nt) << 9)
                      + ((lkgc << 4) + lrow) * 8 + joff) = pk;
    }
}

// ---------------- logits via MFMA ----------------
__global__ __launch_bounds__(256) void k_logits2(
    const float* __restrict__ z, const float* __restrict__ mask,
    const float* __restrict__ gz, const float* __restrict__ bz,
    const u16* __restrict__ wzT, const float* __restrict__ bzb,
    float* __restrict__ wbuf)
{
    const int tid   = threadIdx.x;
    const int wid   = tid >> 6;
    const int lane  = tid & 63;
    const int lrow  = lane & 15;
    const int lkg   = lane >> 4;
    const int pair0 = (blockIdx.x * 4 + wid) * 16;

    float x[4][8];
    float s1 = 0.0f, s2 = 0.0f;
    #pragma unroll
    for (int ks = 0; ks < 4; ks++) {
        const float4* zp = (const float4*)(z + (size_t)(pair0 + lrow) * 128 + ks * 32 + lkg * 8);
        const float4 a = zp[0], b = zp[1];
        x[ks][0] = a.x; x[ks][1] = a.y; x[ks][2] = a.z; x[ks][3] = a.w;
        x[ks][4] = b.x; x[ks][5] = b.y; x[ks][6] = b.z; x[ks][7] = b.w;
        #pragma unroll
        for (int j = 0; j < 8; j++) { s1 += x[ks][j]; s2 += x[ks][j] * x[ks][j]; }
    }
    s1 += __shfl_xor(s1, 16); s1 += __shfl_xor(s1, 32);
    s2 += __shfl_xor(s2, 16); s2 += __shfl_xor(s2, 32);
    const float mean = s1 * (1.0f / 128.0f);
    const float var  = s2 * (1.0f / 128.0f) - mean * mean;
    const float rs   = rsqrtf(var + EPSV);

    float4v acc = (float4v){0.f, 0.f, 0.f, 0.f};
    #pragma unroll
    for (int ks = 0; ks < 4; ks++) {
        const int c0 = ks * 32 + lkg * 8;
        const float4 g0 = *(const float4*)(gz + c0);
        const float4 g1 = *(const float4*)(gz + c0 + 4);
        const float4 b0 = *(const float4*)(bz + c0);
        const float4 b1 = *(const float4*)(bz + c0 + 4);
        const float gv[8] = {g0.x, g0.y, g0.z, g0.w, g1.x, g1.y, g1.z, g1.w};
        const float bvv[8] = {b0.x, b0.y, b0.z, b0.w, b1.x, b1.y, b1.z, b1.w};
        short8 afr;
        #pragma unroll
        for (int j = 0; j < 8; j++)
            afr[j] = (short)f2us((x[ks][j] - mean) * rs * gv[j] + bvv[j]);
        const short8 bfr = *(const short8*)(wzT + (size_t)lrow * 128 + c0);
        acc = __builtin_amdgcn_mfma_f32_16x16x32_bf16(afr, bfr, acc, 0, 0, 0);
    }
    if (lrow < 8) {
        const float bzv = bzb[lrow];
        #pragma unroll
        for (int r = 0; r < 4; r++) {
            const int p = pair0 + lkg * 4 + r;
            const float mb = INFV * (mask[p] - 1.0f);
            wbuf[(size_t)lrow * 147456 + p] = acc[r] + bzv + mb;
        }
    }
}

// ---------------- softmax -> FRAGMENT-ORDERED wbf[qb][h][kt][mt][lane][8] ----------------
// Consumer A-frag read = contiguous 1KB per (qb,h,kt,mt). Writer scatters 2B stores
// (8x 16B-contiguous groups per wave-store) -- acceptable, softmax is tiny.
__global__ __launch_bounds__(256) void k_softmax_f(
    const float* __restrict__ wbuf, u16* __restrict__ wbf)
{
    const int r = blockIdx.x * 4 + (threadIdx.x >> 6);   // r = h*384 + q
    const int lane = threadIdx.x & 63;
    const float* base = wbuf + (size_t)r * 384;
    float v[6];
    float mx = -1e30f;
    #pragma unroll
    for (int j = 0; j < 6; j++) {
        v[j] = base[lane + j * 64];
        mx = fmaxf(mx, v[j]);
    }
    mx = wred_max(mx);
    float s = 0.0f;
    #pragma unroll
    for (int j = 0; j < 6; j++) {
        v[j] = __expf(v[j] - mx);
        s += v[j];
    }
    s = wred_sum(s);
    const float inv = 1.0f / s;

    const int h  = r / 384;
    const int q  = r - h * 384;
    const int qb = q >> 5;
    const int mt = (q >> 4) & 1;
    const int lr = q & 15;
    #pragma unroll
    for (int j = 0; j < 6; j++) {
        const int k   = lane + j * 64;
        const int kt  = k >> 5;
        const int lkg = (k >> 3) & 3;
        const int jj  = k & 7;
        wbf[((((size_t)(qb * 8 + h) * 12 + kt) * 2 + mt) << 9) + ((lkg << 4) + lr) * 8 + jj]
            = f2us(v[j] * inv);
    }
}

// ---------------- legacy softmax (row-major wb16) for fallback path ----------------
__global__ __launch_bounds__(256) void k_softmax(
    const float* __restrict__ wbuf, u16* __restrict__ wb16)
{
    const int r = blockIdx.x * 4 + (threadIdx.x >> 6);
    const int lane = threadIdx.x & 63;
    const float* base = wbuf + (size_t)r * 384;
    float v[6];
    float mx = -1e30f;
    #pragma unroll
    for (int j = 0; j < 6; j++) {
        v[j] = base[lane + j * 64];
        mx = fmaxf(mx, v[j]);
    }
    mx = wred_max(mx);
    float s = 0.0f;
    #pragma unroll
    for (int j = 0; j < 6; j++) {
        v[j] = __expf(v[j] - mx);
        s += v[j];
    }
    s = wred_sum(s);
    const float inv = 1.0f / s;
    u16* ob = wb16 + (size_t)r * 384;
    #pragma unroll
    for (int j = 0; j < 6; j++) ob[lane + j * 64] = f2us(v[j] * inv);
}

// ---------------- fused7: 8-wave block, coalesced frag loads, barrier-free main loop ----------------
// block = 512 thr = 8 waves: wave (wq = w>>1, wh = w&1) owns 32q x 128hc.
// oacc = 16 frags (64 AGPR) -> total regs ~110 -> 4 waves/SIMD (2 blocks/CU, 50% occ).
// All main-loop A/B loads are contiguous-1KB wave-loads from frag-ordered wbf/vTf.
__global__ __launch_bounds__(512, 4) void k_fused7(
    const u16* __restrict__ mn, const u16* __restrict__ vTf,
    const float* __restrict__ bv, const float* __restrict__ bg, const float* __restrict__ bo,
    const u16* __restrict__ wg_t, const u16* __restrict__ wo_t,
    const u16* __restrict__ wbf, float* __restrict__ out)
{
    __shared__ __align__(16) u16 og[128 * 264];   // epilogue o*g tile (67584 B)

    const int tid  = threadIdx.x;
    const int w    = tid >> 6;
    const int wq   = w >> 1;          // 0..3  q-band
    const int wh   = w & 1;           // 0..1  hc-half
    const int lane = tid & 63;
    const int lrow = lane & 15;
    const int lkg  = lane >> 4;

    // XCD-aware bijective swizzle: 1536 blocks = 8 * 192
    const int bid  = blockIdx.x;
    const int xcd  = bid & 7;
    const int slot = bid >> 3;          // 0..191
    const int sdiv = slot / 3;          // 0..63
    const int q0   = (slot - sdiv * 3) * 128;
    const int s    = sdiv * 8 + xcd;    // 0..511

    const int qb = (q0 >> 5) + wq;      // 32-row q-block index 0..11

    // oacc[mt*8+nt]: q rows q0+wq*32+mt*16.., hc = wh*128+nt*16+lrow. Init = bv.
    float4v oacc[16];
    #pragma unroll
    for (int mt = 0; mt < 2; mt++)
        #pragma unroll
        for (int nt = 0; nt < 8; nt++) {
            const float b = bv[wh * 128 + nt * 16 + lrow];
            oacc[mt * 8 + nt] = (float4v){b, b, b, b};
        }

    for (int kt = 0; kt < 12; kt++) {
        short8 bb[8];
        #pragma unroll
        for (int nt = 0; nt < 8; nt++) {
            const int ntg = wh * 8 + nt;
            bb[nt] = *(const short8*)(vTf + ((((size_t)s * 12 + kt) * 16 + ntg) << 9) + lane * 8);
        }
        #pragma unroll
        for (int hl = 0; hl < 4; hl++) {
            const int h = wh * 4 + hl;
            const size_t abase = (((size_t)(qb * 8 + h) * 12 + kt) * 2) << 9;
            const short8 a0 = *(const short8*)(wbf + abase + lane * 8);
            const short8 a1 = *(const short8*)(wbf + abase + 512 + lane * 8);
            #pragma unroll
            for (int sub = 0; sub < 2; sub++) {
                const int nt = hl * 2 + sub;
                oacc[nt]     = __builtin_amdgcn_mfma_f32_16x16x32_bf16(a0, bb[nt], oacc[nt], 0, 0, 0);
                oacc[8 + nt] = __builtin_amdgcn_mfma_f32_16x16x32_bf16(a1, bb[nt], oacc[8 + nt], 0, 0, 0);
            }
        }
    }

    // ---- g-GEMM + sigmoid + o*g -> og ----
    {
        const u16* mnq = mn + ((size_t)s * 384 + q0 + wq * 32 + lrow) * 64;
        #pragma unroll
        for (int mt = 0; mt < 2; mt++) {
            const short8 a0 = *(const short8*)(mnq + mt * 1024 + lkg * 8);
            const short8 a1 = *(const short8*)(mnq + mt * 1024 + 32 + lkg * 8);
            #pragma unroll
            for (int nt = 0; nt < 8; nt++) {
                const int hc0 = wh * 128 + nt * 16;
                const float bgv = bg[hc0 + lrow];
                const short8 b0 = *(const short8*)(wg_t + (size_t)(hc0 + lrow) * 64 + lkg * 8);
                const short8 b1 = *(const short8*)(wg_t + (size_t)(hc0 + lrow) * 64 + 32 + lkg * 8);
                float4v gacc = (float4v){bgv, bgv, bgv, bgv};
                gacc = __builtin_amdgcn_mfma_f32_16x16x32_bf16(a0, b0, gacc, 0, 0, 0);
                gacc = __builtin_amdgcn_mfma_f32_16x16x32_bf16(a1, b1, gacc, 0, 0, 0);
                #pragma unroll
                for (int r = 0; r < 4; r++) {
                    const float sg = 1.0f / (1.0f + __expf(-gacc[r]));
                    og[(size_t)(wq * 32 + mt * 16 + lkg * 4 + r) * 264 + hc0 + lrow]
                        = f2us(oacc[mt * 8 + nt][r] * sg);
                }
            }
        }
    }
    __syncthreads();

    // ---- out-GEMM: A from og (LDS), out cols split by wh ----
    #pragma unroll
    for (int mt = 0; mt < 2; mt++) {
        short8 af[8];
        #pragma unroll
        for (int ks = 0; ks < 8; ks++)
            af[ks] = *(const short8*)&og[(size_t)(wq * 32 + mt * 16 + lrow) * 264 + ks * 32 + lkg * 8];
        #pragma unroll
        for (int ntl = 0; ntl < 2; ntl++) {
            const int nto = wh * 2 + ntl;
            const float bov = bo[nto * 16 + lrow];
            float4v fac = (float4v){bov, bov, bov, bov};
            #pragma unroll
            for (int ks = 0; ks < 8; ks++) {
                const short8 b = *(const short8*)(wo_t + (size_t)(nto * 16 + lrow) * 256 + ks * 32 + lkg * 8);
                fac = __builtin_amdgcn_mfma_f32_16x16x32_bf16(af[ks], b, fac, 0, 0, 0);
            }
            #pragma unroll
            for (int r = 0; r < 4; r++)
                out[((size_t)s * 384 + q0 + wq * 32 + mt * 16 + lkg * 4 + r) * 64 + nto * 16 + lrow]
                    = fac[r];
        }
    }
}

// ---------------- fallback (round-0 kernel) if workspace can't fit vT ----------------
__global__ __launch_bounds__(256, 2) void k_fused4(
    const u16* __restrict__ mn,
    const float* __restrict__ bv, const float* __restrict__ bg, const float* __restrict__ bo,
    const u16* __restrict__ wv_t, const u16* __restrict__ wg_t, const u16* __restrict__ wo_t,
    const u16* __restrict__ wb16, float* __restrict__ out)
{
    __shared__ __align__(16) char smem[67584];
    u16* vtt = (u16*)smem;
    u16* og  = (u16*)smem;

    const int tid  = threadIdx.x;
    const int wid  = tid >> 6;
    const int lane = tid & 63;
    const int lrow = lane & 15;
    const int lkg  = lane >> 4;
    const int s    = blockIdx.y;
    const int q0   = blockIdx.x * 128;

    const int vmt  = wid & 1;
    const int vnt0 = (wid >> 1) * 8;

    float4v oacc[32];
    #pragma unroll
    for (int mt = 0; mt < 2; mt++)
        #pragma unroll
        for (int nt = 0; nt < 16; nt++) {
            const float b = bv[nt * 16 + lrow];
            oacc[mt * 16 + nt] = (float4v){b, b, b, b};
        }

    for (int kt = 0; kt < 12; kt++) {
        const int k0 = kt * 32;
        float4v vacc[8];
        #pragma unroll
        for (int nt = 0; nt < 8; nt++) vacc[nt] = (float4v){0.f, 0.f, 0.f, 0.f};
        const u16* mnk = mn + ((size_t)s * 384 + k0 + vmt * 16 + lrow) * 64;
        #pragma unroll
        for (int ks = 0; ks < 2; ks++) {
            const short8 a = *(const short8*)(mnk + ks * 32 + lkg * 8);
            #pragma unroll
            for (int nt = 0; nt < 8; nt++) {
                const short8 b = *(const short8*)(wv_t + (size_t)((vnt0 + nt) * 16 + lrow) * 64 + ks * 32 + lkg * 8);
                vacc[nt] = __builtin_amdgcn_mfma_f32_16x16x32_bf16(a, b, vacc[nt], 0, 0, 0);
            }
        }
        u16* vb = vtt + (size_t)(kt & 1) * 8192;
        const int kg8 = vmt * 2 + (lkg >> 1);
        const int ko  = (lkg & 1) * 4;
        #pragma unroll
        for (int nt = 0; nt < 8; nt++) {
            uint2 pk;
            pk.x = (u32)f2us(vacc[nt][0]) | ((u32)f2us(vacc[nt][1]) << 16);
            pk.y = (u32)f2us(vacc[nt][2]) | ((u32)f2us(vacc[nt][3]) << 16);
            *(uint2*)&vb[((size_t)kg8 * 256 + (vnt0 + nt) * 16 + lrow) * 8 + ko] = pk;
        }
        __syncthreads();

        short8 ah[2][8];
        #pragma unroll
        for (int mt = 0; mt < 2; mt++)
            #pragma unroll
            for (int h = 0; h < 8; h++)
                ah[mt][h] = *(const short8*)(wb16 + (size_t)h * 147456
                              + (size_t)(q0 + wid * 32 + mt * 16 + lrow) * 384 + k0 + lkg * 8);
        #pragma unroll
        for (int nt = 0; nt < 16; nt++) {
            const short8 b = *(const short8*)&vb[((size_t)lkg * 256 + nt * 16 + lrow) * 8];
            oacc[nt]      = __builtin_amdgcn_mfma_f32_16x16x32_bf16(ah[0][nt >> 1], b, oacc[nt], 0, 0, 0);
            oacc[16 + nt] = __builtin_amdgcn_mfma_f32_16x16x32_bf16(ah[1][nt >> 1], b, oacc[16 + nt], 0, 0, 0);
        }
    }
    __syncthreads();

    #pragma unroll
    for (int mt = 0; mt < 2; mt++) {
        const u16* mnq = mn + ((size_t)s * 384 + q0 + wid * 32 + mt * 16 + lrow) * 64;
        const short8 a0 = *(const short8*)(mnq + lkg * 8);
        const short8 a1 = *(const short8*)(mnq + 32 + lkg * 8);
        #pragma unroll
        for (int nt = 0; nt < 16; nt++) {
            const float bgv = bg[nt * 16 + lrow];
            float4v gacc = (float4v){bgv, bgv, bgv, bgv};
            const short8 b0 = *(const short8*)(wg_t + (size_t)(nt * 16 + lrow) * 64 + lkg * 8);
            const short8 b1 = *(const short8*)(wg_t + (size_t)(nt * 16 + lrow) * 64 + 32 + lkg * 8);
            gacc = __builtin_amdgcn_mfma_f32_16x16x32_bf16(a0, b0, gacc, 0, 0, 0);
            gacc = __builtin_amdgcn_mfma_f32_16x16x32_bf16(a1, b1, gacc, 0, 0, 0);
            #pragma unroll
            for (int r = 0; r < 4; r++) {
                const float sg = 1.0f / (1.0f + __expf(-gacc[r]));
                og[(size_t)(wid * 32 + mt * 16 + lkg * 4 + r) * 264 + nt * 16 + lrow]
                    = f2us(oacc[mt * 16 + nt][r] * sg);
            }
        }
    }
    __syncthreads();

    #pragma unroll
    for (int mt = 0; mt < 2; mt++) {
        short8 af[8];
        #pragma unroll
        for (int ks = 0; ks < 8; ks++)
            af[ks] = *(const short8*)&og[(size_t)(wid * 32 + mt * 16 + lrow) * 264 + ks * 32 + lkg * 8];
        #pragma unroll
        for (int nt = 0; nt < 4; nt++) {
            const float bov = bo[nt * 16 + lrow];
            float4v fac = (float4v){bov, bov, bov, bov};
            #pragma unroll
            for (int ks = 0; ks < 8; ks++) {
                const short8 b = *(const short8*)(wo_t + (size_t)(nt * 16 + lrow) * 256 + ks * 32 + lkg * 8);
                fac = __builtin_amdgcn_mfma_f32_16x16x32_bf16(af[ks], b, fac, 0, 0, 0);
            }
            #pragma unroll
            for (int r = 0; r < 4; r++)
                out[((size_t)s * 384 + q0 + wid * 32 + mt * 16 + lkg * 4 + r) * 64 + nt * 16 + lrow]
                    = fac[r];
        }
    }
}

extern "C" void kernel_launch(void* const* d_in, const int* in_sizes, int n_in,
                              void* d_out, int out_size, void* d_ws, size_t ws_size,
                              hipStream_t stream) {
    const float* m    = (const float*)d_in[0];
    const float* z    = (const float*)d_in[1];
    const float* mask = (const float*)d_in[2];
    const float* gm   = (const float*)d_in[3];
    const float* bm   = (const float*)d_in[4];
    const float* gz   = (const float*)d_in[5];
    const float* bz   = (const float*)d_in[6];
    const float* wz   = (const float*)d_in[7];
    const float* bzb  = (const float*)d_in[8];
    const float* wv   = (const float*)d_in[9];
    const float* bv   = (const float*)d_in[10];
    const float* wg   = (const float*)d_in[11];
    const float* bg   = (const float*)d_in[12];
    const float* wo   = (const float*)d_in[13];
    const float* bo   = (const float*)d_in[14];
    float* out = (float*)d_out;

    // ws layout
    char* ws = (char*)d_ws;
    float* wbuf = (float*)ws;                       // [8][147456] fp32 logits   4,718,592 B
    u16*  wb16  = (u16*)(ws + 4718592);             // weights bf16 (row-major OR frag) 2,359,296 B
    u16*  mn    = (u16*)(ws + 7077888);             // [196608][64] bf16 LN(m)  25,165,824 B
    u16*  wv_t  = (u16*)(ws + 32243712);            // [256][64]  bf16
    u16*  wg_t  = (u16*)(ws + 32276480);            // [256][64]  bf16
    u16*  wo_t  = (u16*)(ws + 32309248);            // [64][256]  bf16
    u16*  wzT   = (u16*)(ws + 32342016);            // [16][128]  bf16
    u16*  vTf   = (u16*)(ws + 32346112);            // frag-ordered vT 100,663,296 B

    const bool big = ws_size >= 133009408ull;

    k_prep_ln<<<12488, 256, 0, stream>>>(m, gm, bm, mn, wv, wg, wo, wz, wv_t, wg_t, wo_t, wzT);
    if (big)
        k_vT<<<dim3(6, 512), 256, 0, stream>>>(mn, wv_t, vTf);
    k_logits2<<<2304, 256, 0, stream>>>(z, mask, gz, bz, wzT, bzb, wbuf);
    if (big) {
        k_softmax_f<<<768, 256, 0, stream>>>(wbuf, wb16);
        k_fused7<<<1536, 512, 0, stream>>>(mn, vTf, bv, bg, bo, wg_t, wo_t, wb16, out);
    } else {
        k_softmax<<<768, 256, 0, stream>>>(wbuf, wb16);
        k_fused4<<<dim3(3, 512), 256, 0, stream>>>(mn, bv, bg, bo, wv_t, wg_t, wo_t, wb16, out);
    }
}

// Round 4
// 389.232 us; speedup vs baseline: 1.4086x; 1.0853x over previous
//
#include <hip/hip_runtime.h>
#include <hip/hip_bf16.h>

#define INFV 1e9f
#define EPSV 1e-5f

typedef unsigned short u16;
typedef unsigned int u32;
typedef __attribute__((ext_vector_type(8))) short short8;   // 8 bf16 (MFMA A/B frag)
typedef __attribute__((ext_vector_type(4))) float float4v;  // MFMA C/D frag

__device__ __forceinline__ u16 f2us(float f) {
    u32 v;
    __builtin_memcpy(&v, &f, 4);
    u32 r = v + 0x7fffu + ((v >> 16) & 1u);
    return (u16)(r >> 16);
}

__device__ __forceinline__ float wred_sum(float x) {
    #pragma unroll
    for (int o = 32; o; o >>= 1) x += __shfl_xor(x, o);
    return x;
}
__device__ __forceinline__ float wred_max(float x) {
    #pragma unroll
    for (int o = 32; o; o >>= 1) x = fmaxf(x, __shfl_xor(x, o));
    return x;
}

// async global->LDS, 16B per lane; LDS dest = wave-uniform base + lane*16
__device__ __forceinline__ void gld16(const void* g, void* l) {
    __builtin_amdgcn_global_load_lds(
        (const __attribute__((address_space(1))) unsigned int*)g,
        (__attribute__((address_space(3))) unsigned int*)l,
        16, 0, 0);
}

// ---------------- LN(m) -> mn bf16, + weight prep (merged grid) ----------------
__global__ __launch_bounds__(256) void k_prep_ln(
    const float* __restrict__ m, const float* __restrict__ gm, const float* __restrict__ bm,
    u16* __restrict__ mn,
    const float* __restrict__ wv, const float* __restrict__ wg,
    const float* __restrict__ wo, const float* __restrict__ wz,
    u16* __restrict__ wv_t, u16* __restrict__ wg_t,
    u16* __restrict__ wo_t, u16* __restrict__ wzT)
{
    if (blockIdx.x < 12288) {
        const int tid  = threadIdx.x;
        const int wid  = tid >> 6;
        const int lane = tid & 63;
        const int rloc = lane >> 4;
        const int c4   = (lane & 15) * 4;
        const int row  = blockIdx.x * 16 + wid * 4 + rloc;   // 0..196607
        const float4 x = *(const float4*)(m + (size_t)row * 64 + c4);
        float s1 = x.x + x.y + x.z + x.w;
        float s2 = x.x * x.x + x.y * x.y + x.z * x.z + x.w * x.w;
        #pragma unroll
        for (int o = 8; o; o >>= 1) { s1 += __shfl_xor(s1, o); s2 += __shfl_xor(s2, o); }
        const float mean = s1 * (1.0f / 64.0f);
        const float var  = s2 * (1.0f / 64.0f) - mean * mean;
        const float rs   = rsqrtf(var + EPSV);
        const float4 g = *(const float4*)(gm + c4);
        const float4 b = *(const float4*)(bm + c4);
        uint2 pk;
        pk.x = (u32)f2us((x.x - mean) * rs * g.x + b.x) | ((u32)f2us((x.y - mean) * rs * g.y + b.y) << 16);
        pk.y = (u32)f2us((x.z - mean) * rs * g.z + b.z) | ((u32)f2us((x.w - mean) * rs * g.w + b.w) << 16);
        *(uint2*)(mn + (size_t)row * 64 + c4) = pk;
    } else {
        const int i = (blockIdx.x - 12288) * 256 + threadIdx.x;   // 0..51199
        if (i < 16384) {
            const int n = i >> 6, k = i & 63;
            wv_t[i] = f2us(wv[(size_t)k * 256 + n]);
        } else if (i < 32768) {
            const int j = i - 16384, n = j >> 6, k = j & 63;
            wg_t[j] = f2us(wg[(size_t)k * 256 + n]);
        } else if (i < 49152) {
            const int j = i - 32768, n = j >> 8, k = j & 255;
            wo_t[j] = f2us(wo[(size_t)k * 64 + n]);
        } else if (i < 51200) {
            const int j = i - 49152, n = j >> 7, k = j & 127;
            wzT[j] = (n < 8) ? f2us(wz[(size_t)k * 8 + n]) : (u16)0;
        }
    }
}

// ---------------- vT producer -> FRAGMENT-ORDERED vTf[s][kt][nt][lane][8] ----------------
__global__ __launch_bounds__(256) void k_vT(
    const u16* __restrict__ mn, const u16* __restrict__ wv_t, u16* __restrict__ vTf)
{
    const int tid  = threadIdx.x;
    const int wid  = tid >> 6;
    const int lane = tid & 63;
    const int lrow = lane & 15;
    const int lkg  = lane >> 4;
    const int s    = blockIdx.y;
    const int k0   = blockIdx.x * 64 + wid * 16;   // this wave's 16 k-rows

    const int kt   = blockIdx.x * 2 + (wid >> 1);  // 32-k chunk index
    const int lkgc = (wid & 1) * 2 + (lkg >> 1);   // k-subgroup within chunk
    const int joff = (lkg & 1) * 4;

    const u16* mnk = mn + ((size_t)s * 384 + k0 + lrow) * 64;
    const short8 a0 = *(const short8*)(mnk + lkg * 8);
    const short8 a1 = *(const short8*)(mnk + 32 + lkg * 8);

    #pragma unroll
    for (int nt = 0; nt < 16; nt++) {
        const short8 b0 = *(const short8*)(wv_t + (size_t)(nt * 16 + lrow) * 64 + lkg * 8);
        const short8 b1 = *(const short8*)(wv_t + (size_t)(nt * 16 + lrow) * 64 + 32 + lkg * 8);
        float4v acc = (float4v){0.f, 0.f, 0.f, 0.f};
        acc = __builtin_amdgcn_mfma_f32_16x16x32_bf16(a0, b0, acc, 0, 0, 0);
        acc = __builtin_amdgcn_mfma_f32_16x16x32_bf16(a1, b1, acc, 0, 0, 0);
        uint2 pk;
        pk.x = (u32)f2us(acc[0]) | ((u32)f2us(acc[1]) << 16);
        pk.y = (u32)f2us(acc[2]) | ((u32)f2us(acc[3]) << 16);
        *(uint2*)(vTf + ((((size_t)s * 12 + kt) * 16 + nt) << 9)
                      + ((lkgc << 4) + lrow) * 8 + joff) = pk;
    }
}

// ---------------- logits via MFMA ----------------
__global__ __launch_bounds__(256) void k_logits2(
    const float* __restrict__ z, const float* __restrict__ mask,
    const float* __restrict__ gz, const float* __restrict__ bz,
    const u16* __restrict__ wzT, const float* __restrict__ bzb,
    float* __restrict__ wbuf)
{
    const int tid   = threadIdx.x;
    const int wid   = tid >> 6;
    const int lane  = tid & 63;
    const int lrow  = lane & 15;
    const int lkg   = lane >> 4;
    const int pair0 = (blockIdx.x * 4 + wid) * 16;

    float x[4][8];
    float s1 = 0.0f, s2 = 0.0f;
    #pragma unroll
    for (int ks = 0; ks < 4; ks++) {
        const float4* zp = (const float4*)(z + (size_t)(pair0 + lrow) * 128 + ks * 32 + lkg * 8);
        const float4 a = zp[0], b = zp[1];
        x[ks][0] = a.x; x[ks][1] = a.y; x[ks][2] = a.z; x[ks][3] = a.w;
        x[ks][4] = b.x; x[ks][5] = b.y; x[ks][6] = b.z; x[ks][7] = b.w;
        #pragma unroll
        for (int j = 0; j < 8; j++) { s1 += x[ks][j]; s2 += x[ks][j] * x[ks][j]; }
    }
    s1 += __shfl_xor(s1, 16); s1 += __shfl_xor(s1, 32);
    s2 += __shfl_xor(s2, 16); s2 += __shfl_xor(s2, 32);
    const float mean = s1 * (1.0f / 128.0f);
    const float var  = s2 * (1.0f / 128.0f) - mean * mean;
    const float rs   = rsqrtf(var + EPSV);

    float4v acc = (float4v){0.f, 0.f, 0.f, 0.f};
    #pragma unroll
    for (int ks = 0; ks < 4; ks++) {
        const int c0 = ks * 32 + lkg * 8;
        const float4 g0 = *(const float4*)(gz + c0);
        const float4 g1 = *(const float4*)(gz + c0 + 4);
        const float4 b0 = *(const float4*)(bz + c0);
        const float4 b1 = *(const float4*)(bz + c0 + 4);
        const float gv[8] = {g0.x, g0.y, g0.z, g0.w, g1.x, g1.y, g1.z, g1.w};
        const float bvv[8] = {b0.x, b0.y, b0.z, b0.w, b1.x, b1.y, b1.z, b1.w};
        short8 afr;
        #pragma unroll
        for (int j = 0; j < 8; j++)
            afr[j] = (short)f2us((x[ks][j] - mean) * rs * gv[j] + bvv[j]);
        const short8 bfr = *(const short8*)(wzT + (size_t)lrow * 128 + c0);
        acc = __builtin_amdgcn_mfma_f32_16x16x32_bf16(afr, bfr, acc, 0, 0, 0);
    }
    if (lrow < 8) {
        const float bzv = bzb[lrow];
        #pragma unroll
        for (int r = 0; r < 4; r++) {
            const int p = pair0 + lkg * 4 + r;
            const float mb = INFV * (mask[p] - 1.0f);
            wbuf[(size_t)lrow * 147456 + p] = acc[r] + bzv + mb;
        }
    }
}

// ---------------- softmax -> FRAGMENT-ORDERED wbf[qb][h][kt][mt][lane][8] ----------------
__global__ __launch_bounds__(256) void k_softmax_f(
    const float* __restrict__ wbuf, u16* __restrict__ wbf)
{
    const int r = blockIdx.x * 4 + (threadIdx.x >> 6);   // r = h*384 + q
    const int lane = threadIdx.x & 63;
    const float* base = wbuf + (size_t)r * 384;
    float v[6];
    float mx = -1e30f;
    #pragma unroll
    for (int j = 0; j < 6; j++) {
        v[j] = base[lane + j * 64];
        mx = fmaxf(mx, v[j]);
    }
    mx = wred_max(mx);
    float s = 0.0f;
    #pragma unroll
    for (int j = 0; j < 6; j++) {
        v[j] = __expf(v[j] - mx);
        s += v[j];
    }
    s = wred_sum(s);
    const float inv = 1.0f / s;

    const int h  = r / 384;
    const int q  = r - h * 384;
    const int qb = q >> 5;
    const int mt = (q >> 4) & 1;
    const int lr = q & 15;
    #pragma unroll
    for (int j = 0; j < 6; j++) {
        const int k   = lane + j * 64;
        const int kt  = k >> 5;
        const int lkg = (k >> 3) & 3;
        const int jj  = k & 7;
        wbf[((((size_t)(qb * 8 + h) * 12 + kt) * 2 + mt) << 9) + ((lkg << 4) + lr) * 8 + jj]
            = f2us(v[j] * inv);
    }
}

// ---------------- legacy softmax (row-major wb16) for fallback path ----------------
__global__ __launch_bounds__(256) void k_softmax(
    const float* __restrict__ wbuf, u16* __restrict__ wb16)
{
    const int r = blockIdx.x * 4 + (threadIdx.x >> 6);
    const int lane = threadIdx.x & 63;
    const float* base = wbuf + (size_t)r * 384;
    float v[6];
    float mx = -1e30f;
    #pragma unroll
    for (int j = 0; j < 6; j++) {
        v[j] = base[lane + j * 64];
        mx = fmaxf(mx, v[j]);
    }
    mx = wred_max(mx);
    float s = 0.0f;
    #pragma unroll
    for (int j = 0; j < 6; j++) {
        v[j] = __expf(v[j] - mx);
        s += v[j];
    }
    s = wred_sum(s);
    const float inv = 1.0f / s;
    u16* ob = wb16 + (size_t)r * 384;
    #pragma unroll
    for (int j = 0; j < 6; j++) ob[lane + j * 64] = f2us(v[j] * inv);
}

// ---------------- fused8: LDS-staged vTf (global_load_lds, double-buffered) ----------------
// Per kt: 8 waves DMA the 16KB vTf chunk ONCE into LDS (was 4x-redundant L2 reads),
// B-frags via conflict-free ds_read_b128, A-frags (wbf) direct from L2.
// 2-phase schedule: stage(kt+1) issued BEFORE compute(kt); one barrier per kt.
// LDS: vtt 2x16KB aliased under the 67.5KB epilogue og tile -> footprint unchanged.
__global__ __launch_bounds__(512, 4) void k_fused8(
    const u16* __restrict__ mn, const u16* __restrict__ vTf,
    const float* __restrict__ bv, const float* __restrict__ bg, const float* __restrict__ bo,
    const u16* __restrict__ wg_t, const u16* __restrict__ wo_t,
    const u16* __restrict__ wbf, float* __restrict__ out)
{
    __shared__ __align__(16) char smem[67584];
    u16* vtt = (u16*)smem;            // [2][16][512] staged vTf frags (32768 B)
    u16* og  = (u16*)smem;            // [128][264] epilogue o*g tile (reuses vtt)

    const int tid  = threadIdx.x;
    const int w    = tid >> 6;
    const int wq   = w >> 1;          // 0..3  q-band
    const int wh   = w & 1;           // 0..1  hc-half
    const int lane = tid & 63;
    const int lrow = lane & 15;
    const int lkg  = lane >> 4;
    const int stg  = w * 2;           // this wave stages frags stg, stg+1

    // XCD-aware bijective swizzle: 1536 blocks = 8 * 192
    const int bid  = blockIdx.x;
    const int xcd  = bid & 7;
    const int slot = bid >> 3;          // 0..191
    const int sdiv = slot / 3;          // 0..63
    const int q0   = (slot - sdiv * 3) * 128;
    const int s    = sdiv * 8 + xcd;    // 0..511

    const int qb = (q0 >> 5) + wq;      // 32-row q-block index 0..11

    // oacc[mt*8+nt]: q rows q0+wq*32+mt*16.., hc = wh*128+nt*16+lrow. Init = bv.
    float4v oacc[16];
    #pragma unroll
    for (int mt = 0; mt < 2; mt++)
        #pragma unroll
        for (int nt = 0; nt < 8; nt++) {
            const float b = bv[wh * 128 + nt * 16 + lrow];
            oacc[mt * 8 + nt] = (float4v){b, b, b, b};
        }

    const u16* vfs = vTf + (((size_t)s * 12) << 13);   // s's [12][16][512] slice

    // prologue: stage kt=0 -> buf 0
    {
        const u16* gp = vfs + ((size_t)stg << 9) + lane * 8;
        u16* lp = vtt + stg * 512;
        gld16(gp, lp);
        gld16(gp + 512, lp + 512);
    }
    __syncthreads();

    for (int kt = 0; kt < 12; kt++) {
        const int cur = kt & 1;
        // stage kt+1 -> other buffer (issued before compute; drained by this kt's barrier)
        if (kt < 11) {
            const u16* gp = vfs + ((((size_t)(kt + 1) * 16) + stg) << 9) + lane * 8;
            u16* lp = vtt + (((cur ^ 1) * 16 + stg) * 512);
            gld16(gp, lp);
            gld16(gp + 512, lp + 512);
        }
        const u16* vb = vtt + cur * 8192;
        #pragma unroll
        for (int hl = 0; hl < 4; hl++) {
            const size_t abase = (((size_t)(qb * 8 + wh * 4 + hl) * 12 + kt) * 2) << 9;
            const short8 a0 = *(const short8*)(wbf + abase + lane * 8);
            const short8 a1 = *(const short8*)(wbf + abase + 512 + lane * 8);
            const short8 b0 = *(const short8*)(vb + ((wh * 8 + hl * 2) * 512) + lane * 8);
            const short8 b1 = *(const short8*)(vb + ((wh * 8 + hl * 2 + 1) * 512) + lane * 8);
            const int nt = hl * 2;
            oacc[nt]         = __builtin_amdgcn_mfma_f32_16x16x32_bf16(a0, b0, oacc[nt], 0, 0, 0);
            oacc[8 + nt]     = __builtin_amdgcn_mfma_f32_16x16x32_bf16(a1, b0, oacc[8 + nt], 0, 0, 0);
            oacc[nt + 1]     = __builtin_amdgcn_mfma_f32_16x16x32_bf16(a0, b1, oacc[nt + 1], 0, 0, 0);
            oacc[8 + nt + 1] = __builtin_amdgcn_mfma_f32_16x16x32_bf16(a1, b1, oacc[8 + nt + 1], 0, 0, 0);
        }
        __syncthreads();
    }

    // ---- g-GEMM + sigmoid + o*g -> og ----
    {
        const u16* mnq = mn + ((size_t)s * 384 + q0 + wq * 32 + lrow) * 64;
        #pragma unroll
        for (int mt = 0; mt < 2; mt++) {
            const short8 a0 = *(const short8*)(mnq + mt * 1024 + lkg * 8);
            const short8 a1 = *(const short8*)(mnq + mt * 1024 + 32 + lkg * 8);
            #pragma unroll
            for (int nt = 0; nt < 8; nt++) {
                const int hc0 = wh * 128 + nt * 16;
                const float bgv = bg[hc0 + lrow];
                const short8 b0 = *(const short8*)(wg_t + (size_t)(hc0 + lrow) * 64 + lkg * 8);
                const short8 b1 = *(const short8*)(wg_t + (size_t)(hc0 + lrow) * 64 + 32 + lkg * 8);
                float4v gacc = (float4v){bgv, bgv, bgv, bgv};
                gacc = __builtin_amdgcn_mfma_f32_16x16x32_bf16(a0, b0, gacc, 0, 0, 0);
                gacc = __builtin_amdgcn_mfma_f32_16x16x32_bf16(a1, b1, gacc, 0, 0, 0);
                #pragma unroll
                for (int r = 0; r < 4; r++) {
                    const float sg = 1.0f / (1.0f + __expf(-gacc[r]));
                    og[(size_t)(wq * 32 + mt * 16 + lkg * 4 + r) * 264 + hc0 + lrow]
                        = f2us(oacc[mt * 8 + nt][r] * sg);
                }
            }
        }
    }
    __syncthreads();

    // ---- out-GEMM: A from og (LDS), out cols split by wh ----
    #pragma unroll
    for (int mt = 0; mt < 2; mt++) {
        short8 af[8];
        #pragma unroll
        for (int ks = 0; ks < 8; ks++)
            af[ks] = *(const short8*)&og[(size_t)(wq * 32 + mt * 16 + lrow) * 264 + ks * 32 + lkg * 8];
        #pragma unroll
        for (int ntl = 0; ntl < 2; ntl++) {
            const int nto = wh * 2 + ntl;
            const float bov = bo[nto * 16 + lrow];
            float4v fac = (float4v){bov, bov, bov, bov};
            #pragma unroll
            for (int ks = 0; ks < 8; ks++) {
                const short8 b = *(const short8*)(wo_t + (size_t)(nto * 16 + lrow) * 256 + ks * 32 + lkg * 8);
                fac = __builtin_amdgcn_mfma_f32_16x16x32_bf16(af[ks], b, fac, 0, 0, 0);
            }
            #pragma unroll
            for (int r = 0; r < 4; r++)
                out[((size_t)s * 384 + q0 + wq * 32 + mt * 16 + lkg * 4 + r) * 64 + nto * 16 + lrow]
                    = fac[r];
        }
    }
}

// ---------------- fallback (round-0 kernel) if workspace can't fit vT ----------------
__global__ __launch_bounds__(256, 2) void k_fused4(
    const u16* __restrict__ mn,
    const float* __restrict__ bv, const float* __restrict__ bg, const float* __restrict__ bo,
    const u16* __restrict__ wv_t, const u16* __restrict__ wg_t, const u16* __restrict__ wo_t,
    const u16* __restrict__ wb16, float* __restrict__ out)
{
    __shared__ __align__(16) char smem[67584];
    u16* vtt = (u16*)smem;
    u16* og  = (u16*)smem;

    const int tid  = threadIdx.x;
    const int wid  = tid >> 6;
    const int lane = tid & 63;
    const int lrow = lane & 15;
    const int lkg  = lane >> 4;
    const int s    = blockIdx.y;
    const int q0   = blockIdx.x * 128;

    const int vmt  = wid & 1;
    const int vnt0 = (wid >> 1) * 8;

    float4v oacc[32];
    #pragma unroll
    for (int mt = 0; mt < 2; mt++)
        #pragma unroll
        for (int nt = 0; nt < 16; nt++) {
            const float b = bv[nt * 16 + lrow];
            oacc[mt * 16 + nt] = (float4v){b, b, b, b};
        }

    for (int kt = 0; kt < 12; kt++) {
        const int k0 = kt * 32;
        float4v vacc[8];
        #pragma unroll
        for (int nt = 0; nt < 8; nt++) vacc[nt] = (float4v){0.f, 0.f, 0.f, 0.f};
        const u16* mnk = mn + ((size_t)s * 384 + k0 + vmt * 16 + lrow) * 64;
        #pragma unroll
        for (int ks = 0; ks < 2; ks++) {
            const short8 a = *(const short8*)(mnk + ks * 32 + lkg * 8);
            #pragma unroll
            for (int nt = 0; nt < 8; nt++) {
                const short8 b = *(const short8*)(wv_t + (size_t)((vnt0 + nt) * 16 + lrow) * 64 + ks * 32 + lkg * 8);
                vacc[nt] = __builtin_amdgcn_mfma_f32_16x16x32_bf16(a, b, vacc[nt], 0, 0, 0);
            }
        }
        u16* vb = vtt + (size_t)(kt & 1) * 8192;
        const int kg8 = vmt * 2 + (lkg >> 1);
        const int ko  = (lkg & 1) * 4;
        #pragma unroll
        for (int nt = 0; nt < 8; nt++) {
            uint2 pk;
            pk.x = (u32)f2us(vacc[nt][0]) | ((u32)f2us(vacc[nt][1]) << 16);
            pk.y = (u32)f2us(vacc[nt][2]) | ((u32)f2us(vacc[nt][3]) << 16);
            *(uint2*)&vb[((size_t)kg8 * 256 + (vnt0 + nt) * 16 + lrow) * 8 + ko] = pk;
        }
        __syncthreads();

        short8 ah[2][8];
        #pragma unroll
        for (int mt = 0; mt < 2; mt++)
            #pragma unroll
            for (int h = 0; h < 8; h++)
                ah[mt][h] = *(const short8*)(wb16 + (size_t)h * 147456
                              + (size_t)(q0 + wid * 32 + mt * 16 + lrow) * 384 + k0 + lkg * 8);
        #pragma unroll
        for (int nt = 0; nt < 16; nt++) {
            const short8 b = *(const short8*)&vb[((size_t)lkg * 256 + nt * 16 + lrow) * 8];
            oacc[nt]      = __builtin_amdgcn_mfma_f32_16x16x32_bf16(ah[0][nt >> 1], b, oacc[nt], 0, 0, 0);
            oacc[16 + nt] = __builtin_amdgcn_mfma_f32_16x16x32_bf16(ah[1][nt >> 1], b, oacc[16 + nt], 0, 0, 0);
        }
    }
    __syncthreads();

    #pragma unroll
    for (int mt = 0; mt < 2; mt++) {
        const u16* mnq = mn + ((size_t)s * 384 + q0 + wid * 32 + mt * 16 + lrow) * 64;
        const short8 a0 = *(const short8*)(mnq + lkg * 8);
        const short8 a1 = *(const short8*)(mnq + 32 + lkg * 8);
        #pragma unroll
        for (int nt = 0; nt < 16; nt++) {
            const float bgv = bg[nt * 16 + lrow];
            float4v gacc = (float4v){bgv, bgv, bgv, bgv};
            const short8 b0 = *(const short8*)(wg_t + (size_t)(nt * 16 + lrow) * 64 + lkg * 8);
            const short8 b1 = *(const short8*)(wg_t + (size_t)(nt * 16 + lrow) * 64 + 32 + lkg * 8);
            gacc = __builtin_amdgcn_mfma_f32_16x16x32_bf16(a0, b0, gacc, 0, 0, 0);
            gacc = __builtin_amdgcn_mfma_f32_16x16x32_bf16(a1, b1, gacc, 0, 0, 0);
            #pragma unroll
            for (int r = 0; r < 4; r++) {
                const float sg = 1.0f / (1.0f + __expf(-gacc[r]));
                og[(size_t)(wid * 32 + mt * 16 + lkg * 4 + r) * 264 + nt * 16 + lrow]
                    = f2us(oacc[mt * 16 + nt][r] * sg);
            }
        }
    }
    __syncthreads();

    #pragma unroll
    for (int mt = 0; mt < 2; mt++) {
        short8 af[8];
        #pragma unroll
        for (int ks = 0; ks < 8; ks++)
            af[ks] = *(const short8*)&og[(size_t)(wid * 32 + mt * 16 + lrow) * 264 + ks * 32 + lkg * 8];
        #pragma unroll
        for (int nt = 0; nt < 4; nt++) {
            const float bov = bo[nt * 16 + lrow];
            float4v fac = (float4v){bov, bov, bov, bov};
            #pragma unroll
            for (int ks = 0; ks < 8; ks++) {
                const short8 b = *(const short8*)(wo_t + (size_t)(nt * 16 + lrow) * 256 + ks * 32 + lkg * 8);
                fac = __builtin_amdgcn_mfma_f32_16x16x32_bf16(af[ks], b, fac, 0, 0, 0);
            }
            #pragma unroll
            for (int r = 0; r < 4; r++)
                out[((size_t)s * 384 + q0 + wid * 32 + mt * 16 + lkg * 4 + r) * 64 + nt * 16 + lrow]
                    = fac[r];
        }
    }
}

extern "C" void kernel_launch(void* const* d_in, const int* in_sizes, int n_in,
                              void* d_out, int out_size, void* d_ws, size_t ws_size,
                              hipStream_t stream) {
    const float* m    = (const float*)d_in[0];
    const float* z    = (const float*)d_in[1];
    const float* mask = (const float*)d_in[2];
    const float* gm   = (const float*)d_in[3];
    const float* bm   = (const float*)d_in[4];
    const float* gz   = (const float*)d_in[5];
    const float* bz   = (const float*)d_in[6];
    const float* wz   = (const float*)d_in[7];
    const float* bzb  = (const float*)d_in[8];
    const float* wv   = (const float*)d_in[9];
    const float* bv   = (const float*)d_in[10];
    const float* wg   = (const float*)d_in[11];
    const float* bg   = (const float*)d_in[12];
    const float* wo   = (const float*)d_in[13];
    const float* bo   = (const float*)d_in[14];
    float* out = (float*)d_out;

    // ws layout
    char* ws = (char*)d_ws;
    float* wbuf = (float*)ws;                       // [8][147456] fp32 logits   4,718,592 B
    u16*  wb16  = (u16*)(ws + 4718592);             // weights bf16 (row-major OR frag) 2,359,296 B
    u16*  mn    = (u16*)(ws + 7077888);             // [196608][64] bf16 LN(m)  25,165,824 B
    u16*  wv_t  = (u16*)(ws + 32243712);            // [256][64]  bf16
    u16*  wg_t  = (u16*)(ws + 32276480);            // [256][64]  bf16
    u16*  wo_t  = (u16*)(ws + 32309248);            // [64][256]  bf16
    u16*  wzT   = (u16*)(ws + 32342016);            // [16][128]  bf16
    u16*  vTf   = (u16*)(ws + 32346112);            // frag-ordered vT 100,663,296 B

    const bool big = ws_size >= 133009408ull;

    k_prep_ln<<<12488, 256, 0, stream>>>(m, gm, bm, mn, wv, wg, wo, wz, wv_t, wg_t, wo_t, wzT);
    if (big)
        k_vT<<<dim3(6, 512), 256, 0, stream>>>(mn, wv_t, vTf);
    k_logits2<<<2304, 256, 0, stream>>>(z, mask, gz, bz, wzT, bzb, wbuf);
    if (big) {
        k_softmax_f<<<768, 256, 0, stream>>>(wbuf, wb16);
        k_fused8<<<1536, 512, 0, stream>>>(mn, vTf, bv, bg, bo, wg_t, wo_t, wb16, out);
    } else {
        k_softmax<<<768, 256, 0, stream>>>(wbuf, wb16);
        k_fused4<<<dim3(3, 512), 256, 0, stream>>>(mn, bv, bg, bo, wv_t, wg_t, wo_t, wb16, out);
    }
}

// Round 6
// 386.881 us; speedup vs baseline: 1.4172x; 1.0061x over previous
//
#include <hip/hip_runtime.h>
#include <hip/hip_bf16.h>

#define INFV 1e9f
#define EPSV 1e-5f

typedef unsigned short u16;
typedef unsigned int u32;
typedef __attribute__((ext_vector_type(8))) short short8;   // 8 bf16 (MFMA A/B frag)
typedef __attribute__((ext_vector_type(4))) float float4v;  // MFMA C/D frag

__device__ __forceinline__ u16 f2us(float f) {
    u32 v;
    __builtin_memcpy(&v, &f, 4);
    u32 r = v + 0x7fffu + ((v >> 16) & 1u);
    return (u16)(r >> 16);
}

__device__ __forceinline__ float wred_sum(float x) {
    #pragma unroll
    for (int o = 32; o; o >>= 1) x += __shfl_xor(x, o);
    return x;
}
__device__ __forceinline__ float wred_max(float x) {
    #pragma unroll
    for (int o = 32; o; o >>= 1) x = fmaxf(x, __shfl_xor(x, o));
    return x;
}

// async global->LDS, 16B per lane; LDS dest = wave-uniform base + lane*16
__device__ __forceinline__ void gld16(const void* g, void* l) {
    __builtin_amdgcn_global_load_lds(
        (const __attribute__((address_space(1))) unsigned int*)g,
        (__attribute__((address_space(3))) unsigned int*)l,
        16, 0, 0);
}

// ---------------- LN(m) -> mn bf16, + weight prep (merged grid) ----------------
__global__ __launch_bounds__(256) void k_prep_ln(
    const float* __restrict__ m, const float* __restrict__ gm, const float* __restrict__ bm,
    u16* __restrict__ mn,
    const float* __restrict__ wv, const float* __restrict__ wg,
    const float* __restrict__ wo, const float* __restrict__ wz,
    u16* __restrict__ wv_t, u16* __restrict__ wg_t,
    u16* __restrict__ wo_t, u16* __restrict__ wzT)
{
    if (blockIdx.x < 12288) {
        const int tid  = threadIdx.x;
        const int wid  = tid >> 6;
        const int lane = tid & 63;
        const int rloc = lane >> 4;
        const int c4   = (lane & 15) * 4;
        const int row  = blockIdx.x * 16 + wid * 4 + rloc;   // 0..196607
        const float4 x = *(const float4*)(m + (size_t)row * 64 + c4);
        float s1 = x.x + x.y + x.z + x.w;
        float s2 = x.x * x.x + x.y * x.y + x.z * x.z + x.w * x.w;
        #pragma unroll
        for (int o = 8; o; o >>= 1) { s1 += __shfl_xor(s1, o); s2 += __shfl_xor(s2, o); }
        const float mean = s1 * (1.0f / 64.0f);
        const float var  = s2 * (1.0f / 64.0f) - mean * mean;
        const float rs   = rsqrtf(var + EPSV);
        const float4 g = *(const float4*)(gm + c4);
        const float4 b = *(const float4*)(bm + c4);
        uint2 pk;
        pk.x = (u32)f2us((x.x - mean) * rs * g.x + b.x) | ((u32)f2us((x.y - mean) * rs * g.y + b.y) << 16);
        pk.y = (u32)f2us((x.z - mean) * rs * g.z + b.z) | ((u32)f2us((x.w - mean) * rs * g.w + b.w) << 16);
        *(uint2*)(mn + (size_t)row * 64 + c4) = pk;
    } else {
        const int i = (blockIdx.x - 12288) * 256 + threadIdx.x;   // 0..51199
        if (i < 16384) {
            const int n = i >> 6, k = i & 63;
            wv_t[i] = f2us(wv[(size_t)k * 256 + n]);
        } else if (i < 32768) {
            const int j = i - 16384, n = j >> 6, k = j & 63;
            wg_t[j] = f2us(wg[(size_t)k * 256 + n]);
        } else if (i < 49152) {
            const int j = i - 32768, n = j >> 8, k = j & 255;
            wo_t[j] = f2us(wo[(size_t)k * 64 + n]);
        } else if (i < 51200) {
            const int j = i - 49152, n = j >> 7, k = j & 127;
            wzT[j] = (n < 8) ? f2us(wz[(size_t)k * 8 + n]) : (u16)0;
        }
    }
}

// ---------------- vT producer -> FRAGMENT-ORDERED vTf[s][kt][nt][lane][8] ----------------
__global__ __launch_bounds__(256) void k_vT(
    const u16* __restrict__ mn, const u16* __restrict__ wv_t, u16* __restrict__ vTf)
{
    const int tid  = threadIdx.x;
    const int wid  = tid >> 6;
    const int lane = tid & 63;
    const int lrow = lane & 15;
    const int lkg  = lane >> 4;
    const int s    = blockIdx.y;
    const int k0   = blockIdx.x * 64 + wid * 16;   // this wave's 16 k-rows

    const int kt   = blockIdx.x * 2 + (wid >> 1);  // 32-k chunk index
    const int lkgc = (wid & 1) * 2 + (lkg >> 1);   // k-subgroup within chunk
    const int joff = (lkg & 1) * 4;

    const u16* mnk = mn + ((size_t)s * 384 + k0 + lrow) * 64;
    const short8 a0 = *(const short8*)(mnk + lkg * 8);
    const short8 a1 = *(const short8*)(mnk + 32 + lkg * 8);

    #pragma unroll
    for (int nt = 0; nt < 16; nt++) {
        const short8 b0 = *(const short8*)(wv_t + (size_t)(nt * 16 + lrow) * 64 + lkg * 8);
        const short8 b1 = *(const short8*)(wv_t + (size_t)(nt * 16 + lrow) * 64 + 32 + lkg * 8);
        float4v acc = (float4v){0.f, 0.f, 0.f, 0.f};
        acc = __builtin_amdgcn_mfma_f32_16x16x32_bf16(a0, b0, acc, 0, 0, 0);
        acc = __builtin_amdgcn_mfma_f32_16x16x32_bf16(a1, b1, acc, 0, 0, 0);
        uint2 pk;
        pk.x = (u32)f2us(acc[0]) | ((u32)f2us(acc[1]) << 16);
        pk.y = (u32)f2us(acc[2]) | ((u32)f2us(acc[3]) << 16);
        *(uint2*)(vTf + ((((size_t)s * 12 + kt) * 16 + nt) << 9)
                      + ((lkgc << 4) + lrow) * 8 + joff) = pk;
    }
}

// ---------------- logits via MFMA ----------------
__global__ __launch_bounds__(256) void k_logits2(
    const float* __restrict__ z, const float* __restrict__ mask,
    const float* __restrict__ gz, const float* __restrict__ bz,
    const u16* __restrict__ wzT, const float* __restrict__ bzb,
    float* __restrict__ wbuf)
{
    const int tid   = threadIdx.x;
    const int wid   = tid >> 6;
    const int lane  = tid & 63;
    const int lrow  = lane & 15;
    const int lkg   = lane >> 4;
    const int pair0 = (blockIdx.x * 4 + wid) * 16;

    float x[4][8];
    float s1 = 0.0f, s2 = 0.0f;
    #pragma unroll
    for (int ks = 0; ks < 4; ks++) {
        const float4* zp = (const float4*)(z + (size_t)(pair0 + lrow) * 128 + ks * 32 + lkg * 8);
        const float4 a = zp[0], b = zp[1];
        x[ks][0] = a.x; x[ks][1] = a.y; x[ks][2] = a.z; x[ks][3] = a.w;
        x[ks][4] = b.x; x[ks][5] = b.y; x[ks][6] = b.z; x[ks][7] = b.w;
        #pragma unroll
        for (int j = 0; j < 8; j++) { s1 += x[ks][j]; s2 += x[ks][j] * x[ks][j]; }
    }
    s1 += __shfl_xor(s1, 16); s1 += __shfl_xor(s1, 32);
    s2 += __shfl_xor(s2, 16); s2 += __shfl_xor(s2, 32);
    const float mean = s1 * (1.0f / 128.0f);
    const float var  = s2 * (1.0f / 128.0f) - mean * mean;
    const float rs   = rsqrtf(var + EPSV);

    float4v acc = (float4v){0.f, 0.f, 0.f, 0.f};
    #pragma unroll
    for (int ks = 0; ks < 4; ks++) {
        const int c0 = ks * 32 + lkg * 8;
        const float4 g0 = *(const float4*)(gz + c0);
        const float4 g1 = *(const float4*)(gz + c0 + 4);
        const float4 b0 = *(const float4*)(bz + c0);
        const float4 b1 = *(const float4*)(bz + c0 + 4);
        const float gv[8] = {g0.x, g0.y, g0.z, g0.w, g1.x, g1.y, g1.z, g1.w};
        const float bvv[8] = {b0.x, b0.y, b0.z, b0.w, b1.x, b1.y, b1.z, b1.w};
        short8 afr;
        #pragma unroll
        for (int j = 0; j < 8; j++)
            afr[j] = (short)f2us((x[ks][j] - mean) * rs * gv[j] + bvv[j]);
        const short8 bfr = *(const short8*)(wzT + (size_t)lrow * 128 + c0);
        acc = __builtin_amdgcn_mfma_f32_16x16x32_bf16(afr, bfr, acc, 0, 0, 0);
    }
    if (lrow < 8) {
        const float bzv = bzb[lrow];
        #pragma unroll
        for (int r = 0; r < 4; r++) {
            const int p = pair0 + lkg * 4 + r;
            const float mb = INFV * (mask[p] - 1.0f);
            wbuf[(size_t)lrow * 147456 + p] = acc[r] + bzv + mb;
        }
    }
}

// ---------------- softmax_f2: per-row softmax + COALESCED frag emission ----------------
// Block = one (h, qb, mt) group = 16 q-rows x 384 k. Each wave owns 4 rows
// (16 lanes/row, 24 floats/lane, xor-reduce over 16 lanes). Scaled bf16 staged in a
// padded LDS tile, then written as contiguous 1KB frag wave-stores (16B/lane).
// Replaces the previous 2-byte-scatter store pattern.
__global__ __launch_bounds__(256) void k_softmax_f2(
    const float* __restrict__ wbuf, u16* __restrict__ wbf)
{
    __shared__ __align__(16) u16 lds[16 * 392];   // rows padded to 392 u16 (784 B)

    const int tid  = threadIdx.x;
    const int w    = tid >> 6;
    const int lane = tid & 63;
    const int rg   = lane >> 4;       // row within wave's group of 4
    const int l16  = lane & 15;

    const int bx = blockIdx.x;        // 0..191
    const int h  = bx & 7;
    const int qm = bx >> 3;           // 0..23
    const int qb = qm >> 1;
    const int mt = qm & 1;
    const int rb = w * 4 + rg;        // 0..15 row in block
    const int q  = qb * 32 + mt * 16 + rb;

    const float* base = wbuf + (size_t)h * 147456 + (size_t)q * 384 + l16 * 24;
    float v[24];
    float mx = -1e30f;
    #pragma unroll
    for (int i = 0; i < 6; i++) {
        const float4 x = *(const float4*)(base + i * 4);
        v[i * 4 + 0] = x.x; v[i * 4 + 1] = x.y; v[i * 4 + 2] = x.z; v[i * 4 + 3] = x.w;
        mx = fmaxf(mx, fmaxf(fmaxf(x.x, x.y), fmaxf(x.z, x.w)));
    }
    #pragma unroll
    for (int o = 8; o; o >>= 1) mx = fmaxf(mx, __shfl_xor(mx, o));
    float s = 0.0f;
    #pragma unroll
    for (int i = 0; i < 24; i++) { v[i] = __expf(v[i] - mx); s += v[i]; }
    #pragma unroll
    for (int o = 8; o; o >>= 1) s += __shfl_xor(s, o);
    const float inv = 1.0f / s;

    u16* lp = lds + rb * 392 + l16 * 24;
    #pragma unroll
    for (int i = 0; i < 12; i++) {
        const u32 pk = (u32)f2us(v[2 * i] * inv) | ((u32)f2us(v[2 * i + 1] * inv) << 16);
        *(u32*)(lp + 2 * i) = pk;
    }
    __syncthreads();

    // wave w emits frags kt = w*3 .. w*3+2 : lane (lkg=lane>>4, lr=lane&15)
    // gathers lds[lr][kt*32 + lkg*8 .. +8] -> contiguous 16B/lane store.
    const int lr  = lane & 15;
    const int lkg = lane >> 4;
    #pragma unroll
    for (int j = 0; j < 3; j++) {
        const int kt = w * 3 + j;
        const short8 f = *(const short8*)(lds + lr * 392 + kt * 32 + lkg * 8);
        *(short8*)(wbf + ((((size_t)(qb * 8 + h) * 12 + kt) * 2 + mt) << 9) + lane * 8) = f;
    }
}

// ---------------- legacy softmax (row-major wb16) for fallback path ----------------
__global__ __launch_bounds__(256) void k_softmax(
    const float* __restrict__ wbuf, u16* __restrict__ wb16)
{
    const int r = blockIdx.x * 4 + (threadIdx.x >> 6);
    const int lane = threadIdx.x & 63;
    const float* base = wbuf + (size_t)r * 384;
    float v[6];
    float mx = -1e30f;
    #pragma unroll
    for (int j = 0; j < 6; j++) {
        v[j] = base[lane + j * 64];
        mx = fmaxf(mx, v[j]);
    }
    mx = wred_max(mx);
    float s = 0.0f;
    #pragma unroll
    for (int j = 0; j < 6; j++) {
        v[j] = __expf(v[j] - mx);
        s += v[j];
    }
    s = wred_sum(s);
    const float inv = 1.0f / s;
    u16* ob = wb16 + (size_t)r * 384;
    #pragma unroll
    for (int j = 0; j < 6; j++) ob[lane + j * 64] = f2us(v[j] * inv);
}

// ---------------- fused9: 2-kt phases (6 barriers), LDS-staged vTf, DB 2x32KB ----------------
// Per phase: stage NEXT 32KB (2 k-chunks) via global_load_lds, compute 2 k-chunks
// (32 MFMA/wave) from current buffer, one __syncthreads. Halves barrier-drain count
// vs fused8 and doubles MFMA work per drain. sub-loop NOT unrolled to cap VGPR at
// fused8's footprint (64 VGPR + 64 AGPR = exactly the 4-waves/SIMD budget).
__global__ __launch_bounds__(512, 4) void k_fused9(
    const u16* __restrict__ mn, const u16* __restrict__ vTf,
    const float* __restrict__ bv, const float* __restrict__ bg, const float* __restrict__ bo,
    const u16* __restrict__ wg_t, const u16* __restrict__ wo_t,
    const u16* __restrict__ wbf, float* __restrict__ out)
{
    __shared__ __align__(16) char smem[67584];
    u16* vtt = (u16*)smem;            // [2][32][512] staged vTf frags (65536 B)
    u16* og  = (u16*)smem;            // [128][264] epilogue o*g tile (reuses vtt)

    const int tid  = threadIdx.x;
    const int w    = tid >> 6;
    const int wq   = w >> 1;          // 0..3  q-band
    const int wh   = w & 1;           // 0..1  hc-half
    const int lane = tid & 63;
    const int lrow = lane & 15;
    const int lkg  = lane >> 4;
    const int stg  = w * 4;           // this wave stages frags stg..stg+3 of the 32

    // XCD-aware bijective swizzle: 1536 blocks = 8 * 192
    const int bid  = blockIdx.x;
    const int xcd  = bid & 7;
    const int slot = bid >> 3;          // 0..191
    const int sdiv = slot / 3;          // 0..63
    const int q0   = (slot - sdiv * 3) * 128;
    const int s    = sdiv * 8 + xcd;    // 0..511

    const int qb = (q0 >> 5) + wq;      // 32-row q-block index 0..11

    // oacc[mt*8+nt]: q rows q0+wq*32+mt*16.., hc = wh*128+nt*16+lrow. Init = bv.
    float4v oacc[16];
    #pragma unroll
    for (int mt = 0; mt < 2; mt++)
        #pragma unroll
        for (int nt = 0; nt < 8; nt++) {
            const float b = bv[wh * 128 + nt * 16 + lrow];
            oacc[mt * 8 + nt] = (float4v){b, b, b, b};
        }

    const u16* vfs = vTf + (((size_t)s * 12) << 13);   // s's [12][16][512] slice

    // prologue: stage phase 0 (k-chunks 0,1) -> buf 0
    {
        const u16* gp = vfs + ((size_t)stg << 9) + lane * 8;
        u16* lp = vtt + stg * 512;
        #pragma unroll
        for (int i = 0; i < 4; i++) gld16(gp + i * 512, lp + i * 512);
    }
    __syncthreads();

    for (int pt = 0; pt < 6; pt++) {
        const int cur = pt & 1;
        // stage phase pt+1 (k-chunks 2pt+2, 2pt+3) -> other buffer
        if (pt < 5) {
            const u16* gp = vfs + ((size_t)((pt + 1) * 32 + stg) << 9) + lane * 8;
            u16* lp = vtt + ((cur ^ 1) * 32 + stg) * 512;
            #pragma unroll
            for (int i = 0; i < 4; i++) gld16(gp + i * 512, lp + i * 512);
        }
        #pragma unroll 1
        for (int sub = 0; sub < 2; sub++) {
            const int kt = pt * 2 + sub;
            const u16* vb = vtt + (cur * 32 + sub * 16) * 512;
            #pragma unroll
            for (int hl = 0; hl < 4; hl++) {
                const size_t abase = (((size_t)(qb * 8 + wh * 4 + hl) * 12 + kt) * 2) << 9;
                const short8 a0 = *(const short8*)(wbf + abase + lane * 8);
                const short8 a1 = *(const short8*)(wbf + abase + 512 + lane * 8);
                const short8 b0 = *(const short8*)(vb + ((wh * 8 + hl * 2) * 512) + lane * 8);
                const short8 b1 = *(const short8*)(vb + ((wh * 8 + hl * 2 + 1) * 512) + lane * 8);
                const int nt = hl * 2;
                oacc[nt]         = __builtin_amdgcn_mfma_f32_16x16x32_bf16(a0, b0, oacc[nt], 0, 0, 0);
                oacc[8 + nt]     = __builtin_amdgcn_mfma_f32_16x16x32_bf16(a1, b0, oacc[8 + nt], 0, 0, 0);
                oacc[nt + 1]     = __builtin_amdgcn_mfma_f32_16x16x32_bf16(a0, b1, oacc[nt + 1], 0, 0, 0);
                oacc[8 + nt + 1] = __builtin_amdgcn_mfma_f32_16x16x32_bf16(a1, b1, oacc[8 + nt + 1], 0, 0, 0);
            }
        }
        __syncthreads();
    }

    // ---- g-GEMM + sigmoid + o*g -> og ----
    {
        const u16* mnq = mn + ((size_t)s * 384 + q0 + wq * 32 + lrow) * 64;
        #pragma unroll
        for (int mt = 0; mt < 2; mt++) {
            const short8 a0 = *(const short8*)(mnq + mt * 1024 + lkg * 8);
            const short8 a1 = *(const short8*)(mnq + mt * 1024 + 32 + lkg * 8);
            #pragma unroll
            for (int nt = 0; nt < 8; nt++) {
                const int hc0 = wh * 128 + nt * 16;
                const float bgv = bg[hc0 + lrow];
                const short8 b0 = *(const short8*)(wg_t + (size_t)(hc0 + lrow) * 64 + lkg * 8);
                const short8 b1 = *(const short8*)(wg_t + (size_t)(hc0 + lrow) * 64 + 32 + lkg * 8);
                float4v gacc = (float4v){bgv, bgv, bgv, bgv};
                gacc = __builtin_amdgcn_mfma_f32_16x16x32_bf16(a0, b0, gacc, 0, 0, 0);
                gacc = __builtin_amdgcn_mfma_f32_16x16x32_bf16(a1, b1, gacc, 0, 0, 0);
                #pragma unroll
                for (int r = 0; r < 4; r++) {
                    const float sg = 1.0f / (1.0f + __expf(-gacc[r]));
                    og[(size_t)(wq * 32 + mt * 16 + lkg * 4 + r) * 264 + hc0 + lrow]
                        = f2us(oacc[mt * 8 + nt][r] * sg);
                }
            }
        }
    }
    __syncthreads();

    // ---- out-GEMM: A from og (LDS), out cols split by wh ----
    #pragma unroll
    for (int mt = 0; mt < 2; mt++) {
        short8 af[8];
        #pragma unroll
        for (int ks = 0; ks < 8; ks++)
            af[ks] = *(const short8*)&og[(size_t)(wq * 32 + mt * 16 + lrow) * 264 + ks * 32 + lkg * 8];
        #pragma unroll
        for (int ntl = 0; ntl < 2; ntl++) {
            const int nto = wh * 2 + ntl;
            const float bov = bo[nto * 16 + lrow];
            float4v fac = (float4v){bov, bov, bov, bov};
            #pragma unroll
            for (int ks = 0; ks < 8; ks++) {
                const short8 b = *(const short8*)(wo_t + (size_t)(nto * 16 + lrow) * 256 + ks * 32 + lkg * 8);
                fac = __builtin_amdgcn_mfma_f32_16x16x32_bf16(af[ks], b, fac, 0, 0, 0);
            }
            #pragma unroll
            for (int r = 0; r < 4; r++)
                out[((size_t)s * 384 + q0 + wq * 32 + mt * 16 + lkg * 4 + r) * 64 + nto * 16 + lrow]
                    = fac[r];
        }
    }
}

// ---------------- fallback (round-0 kernel) if workspace can't fit vT ----------------
__global__ __launch_bounds__(256, 2) void k_fused4(
    const u16* __restrict__ mn,
    const float* __restrict__ bv, const float* __restrict__ bg, const float* __restrict__ bo,
    const u16* __restrict__ wv_t, const u16* __restrict__ wg_t, const u16* __restrict__ wo_t,
    const u16* __restrict__ wb16, float* __restrict__ out)
{
    __shared__ __align__(16) char smem[67584];
    u16* vtt = (u16*)smem;
    u16* og  = (u16*)smem;

    const int tid  = threadIdx.x;
    const int wid  = tid >> 6;
    const int lane = tid & 63;
    const int lrow = lane & 15;
    const int lkg  = lane >> 4;
    const int s    = blockIdx.y;
    const int q0   = blockIdx.x * 128;

    const int vmt  = wid & 1;
    const int vnt0 = (wid >> 1) * 8;

    float4v oacc[32];
    #pragma unroll
    for (int mt = 0; mt < 2; mt++)
        #pragma unroll
        for (int nt = 0; nt < 16; nt++) {
            const float b = bv[nt * 16 + lrow];
            oacc[mt * 16 + nt] = (float4v){b, b, b, b};
        }

    for (int kt = 0; kt < 12; kt++) {
        const int k0 = kt * 32;
        float4v vacc[8];
        #pragma unroll
        for (int nt = 0; nt < 8; nt++) vacc[nt] = (float4v){0.f, 0.f, 0.f, 0.f};
        const u16* mnk = mn + ((size_t)s * 384 + k0 + vmt * 16 + lrow) * 64;
        #pragma unroll
        for (int ks = 0; ks < 2; ks++) {
            const short8 a = *(const short8*)(mnk + ks * 32 + lkg * 8);
            #pragma unroll
            for (int nt = 0; nt < 8; nt++) {
                const short8 b = *(const short8*)(wv_t + (size_t)((vnt0 + nt) * 16 + lrow) * 64 + ks * 32 + lkg * 8);
                vacc[nt] = __builtin_amdgcn_mfma_f32_16x16x32_bf16(a, b, vacc[nt], 0, 0, 0);
            }
        }
        u16* vb = vtt + (size_t)(kt & 1) * 8192;
        const int kg8 = vmt * 2 + (lkg >> 1);
        const int ko  = (lkg & 1) * 4;
        #pragma unroll
        for (int nt = 0; nt < 8; nt++) {
            uint2 pk;
            pk.x = (u32)f2us(vacc[nt][0]) | ((u32)f2us(vacc[nt][1]) << 16);
            pk.y = (u32)f2us(vacc[nt][2]) | ((u32)f2us(vacc[nt][3]) << 16);
            *(uint2*)&vb[((size_t)kg8 * 256 + (vnt0 + nt) * 16 + lrow) * 8 + ko] = pk;
        }
        __syncthreads();

        short8 ah[2][8];
        #pragma unroll
        for (int mt = 0; mt < 2; mt++)
            #pragma unroll
            for (int h = 0; h < 8; h++)
                ah[mt][h] = *(const short8*)(wb16 + (size_t)h * 147456
                              + (size_t)(q0 + wid * 32 + mt * 16 + lrow) * 384 + k0 + lkg * 8);
        #pragma unroll
        for (int nt = 0; nt < 16; nt++) {
            const short8 b = *(const short8*)&vb[((size_t)lkg * 256 + nt * 16 + lrow) * 8];
            oacc[nt]      = __builtin_amdgcn_mfma_f32_16x16x32_bf16(ah[0][nt >> 1], b, oacc[nt], 0, 0, 0);
            oacc[16 + nt] = __builtin_amdgcn_mfma_f32_16x16x32_bf16(ah[1][nt >> 1], b, oacc[16 + nt], 0, 0, 0);
        }
    }
    __syncthreads();

    #pragma unroll
    for (int mt = 0; mt < 2; mt++) {
        const u16* mnq = mn + ((size_t)s * 384 + q0 + wid * 32 + mt * 16 + lrow) * 64;
        const short8 a0 = *(const short8*)(mnq + lkg * 8);
        const short8 a1 = *(const short8*)(mnq + 32 + lkg * 8);
        #pragma unroll
        for (int nt = 0; nt < 16; nt++) {
            const float bgv = bg[nt * 16 + lrow];
            float4v gacc = (float4v){bgv, bgv, bgv, bgv};
            const short8 b0 = *(const short8*)(wg_t + (size_t)(nt * 16 + lrow) * 64 + lkg * 8);
            const short8 b1 = *(const short8*)(wg_t + (size_t)(nt * 16 + lrow) * 64 + 32 + lkg * 8);
            gacc = __builtin_amdgcn_mfma_f32_16x16x32_bf16(a0, b0, gacc, 0, 0, 0);
            gacc = __builtin_amdgcn_mfma_f32_16x16x32_bf16(a1, b1, gacc, 0, 0, 0);
            #pragma unroll
            for (int r = 0; r < 4; r++) {
                const float sg = 1.0f / (1.0f + __expf(-gacc[r]));
                og[(size_t)(wid * 32 + mt * 16 + lkg * 4 + r) * 264 + nt * 16 + lrow]
                    = f2us(oacc[mt * 16 + nt][r] * sg);
            }
        }
    }
    __syncthreads();

    #pragma unroll
    for (int mt = 0; mt < 2; mt++) {
        short8 af[8];
        #pragma unroll
        for (int ks = 0; ks < 8; ks++)
            af[ks] = *(const short8*)&og[(size_t)(wid * 32 + mt * 16 + lrow) * 264 + ks * 32 + lkg * 8];
        #pragma unroll
        for (int nt = 0; nt < 4; nt++) {
            const float bov = bo[nt * 16 + lrow];
            float4v fac = (float4v){bov, bov, bov, bov};
            #pragma unroll
            for (int ks = 0; ks < 8; ks++) {
                const short8 b = *(const short8*)(wo_t + (size_t)(nt * 16 + lrow) * 256 + ks * 32 + lkg * 8);
                fac = __builtin_amdgcn_mfma_f32_16x16x32_bf16(af[ks], b, fac, 0, 0, 0);
            }
            #pragma unroll
            for (int r = 0; r < 4; r++)
                out[((size_t)s * 384 + q0 + wid * 32 + mt * 16 + lkg * 4 + r) * 64 + nt * 16 + lrow]
                    = fac[r];
        }
    }
}

extern "C" void kernel_launch(void* const* d_in, const int* in_sizes, int n_in,
                              void* d_out, int out_size, void* d_ws, size_t ws_size,
                              hipStream_t stream) {
    const float* m    = (const float*)d_in[0];
    const float* z    = (const float*)d_in[1];
    const float* mask = (const float*)d_in[2];
    const float* gm   = (const float*)d_in[3];
    const float* bm   = (const float*)d_in[4];
    const float* gz   = (const float*)d_in[5];
    const float* bz   = (const float*)d_in[6];
    const float* wz   = (const float*)d_in[7];
    const float* bzb  = (const float*)d_in[8];
    const float* wv   = (const float*)d_in[9];
    const float* bv   = (const float*)d_in[10];
    const float* wg   = (const float*)d_in[11];
    const float* bg   = (const float*)d_in[12];
    const float* wo   = (const float*)d_in[13];
    const float* bo   = (const float*)d_in[14];
    float* out = (float*)d_out;

    // ws layout
    char* ws = (char*)d_ws;
    float* wbuf = (float*)ws;                       // [8][147456] fp32 logits   4,718,592 B
    u16*  wb16  = (u16*)(ws + 4718592);             // weights bf16 (row-major OR frag) 2,359,296 B
    u16*  mn    = (u16*)(ws + 7077888);             // [196608][64] bf16 LN(m)  25,165,824 B
    u16*  wv_t  = (u16*)(ws + 32243712);            // [256][64]  bf16
    u16*  wg_t  = (u16*)(ws + 32276480);            // [256][64]  bf16
    u16*  wo_t  = (u16*)(ws + 32309248);            // [64][256]  bf16
    u16*  wzT   = (u16*)(ws + 32342016);            // [16][128]  bf16
    u16*  vTf   = (u16*)(ws + 32346112);            // frag-ordered vT 100,663,296 B

    const bool big = ws_size >= 133009408ull;

    k_prep_ln<<<12488, 256, 0, stream>>>(m, gm, bm, mn, wv, wg, wo, wz, wv_t, wg_t, wo_t, wzT);
    if (big)
        k_vT<<<dim3(6, 512), 256, 0, stream>>>(mn, wv_t, vTf);
    k_logits2<<<2304, 256, 0, stream>>>(z, mask, gz, bz, wzT, bzb, wbuf);
    if (big) {
        k_softmax_f2<<<192, 256, 0, stream>>>(wbuf, wb16);
        k_fused9<<<1536, 512, 0, stream>>>(mn, vTf, bv, bg, bo, wg_t, wo_t, wb16, out);
    } else {
        k_softmax<<<768, 256, 0, stream>>>(wbuf, wb16);
        k_fused4<<<dim3(3, 512), 256, 0, stream>>>(mn, bv, bg, bo, wv_t, wg_t, wo_t, wb16, out);
    }
}